// Round 12
// baseline (256.495 us; speedup 1.0000x reference)
//
#include <hip/hip_runtime.h>
#include <hip/hip_bf16.h>
#include <math.h>

// Problem constants
constexpr int Bn     = 2;
constexpr int Lseq   = 1024;
constexpr int DM     = 512;    // d_model
constexpr int DI     = 1024;   // d_inner
constexpr int DS     = 64;     // d_state
constexpr int RNK    = 32;     // dt_rank
constexpr int NROWS  = Bn * Lseq;  // 2048
constexpr int XDBW   = RNK + 2 * DS; // 160
constexpr int CH     = 64;     // scan chunk length
constexpr int NC     = Lseq / CH;  // 16 chunks

typedef __attribute__((ext_vector_type(4))) float floatx4;
typedef __attribute__((ext_vector_type(8))) short shortx8;

__device__ __forceinline__ float silu_f(float v) {
    return v / (1.f + __expf(-v));
}

__device__ __forceinline__ float rdl(float v, int l) {
    return __int_as_float(__builtin_amdgcn_readlane(__float_as_int(v), l));
}

__device__ __forceinline__ float bf2f(unsigned short u) {
    return __uint_as_float((unsigned)u << 16);
}

// δ(t) for one (row, d): sequential-order dot to bit-match the old delta_kernel
__device__ __forceinline__ float delta_of(const float* __restrict__ xdb, size_t row,
                                          const float* __restrict__ Wdt,
                                          const float* __restrict__ bdt, int d) {
    float acc = bdt[d];
    const float* dtrow = &xdb[row * XDBW];
    #pragma unroll
    for (int r = 0; r < RNK; r += 4) {
        float4 dtv = *(const float4*)&dtrow[r];
        acc += dtv.x * Wdt[(size_t)r * DI + d];
        acc += dtv.y * Wdt[(size_t)(r + 1) * DI + d];
        acc += dtv.z * Wdt[(size_t)(r + 2) * DI + d];
        acc += dtv.w * Wdt[(size_t)(r + 3) * DI + d];
    }
    return (acc > 20.f) ? acc : log1pf(__expf(acc));
}

// ---------------- Fused prep: LN (blocks 0..2047) + 3 weight transposes (2048..2479) ----
__global__ void prep_kernel(const float* __restrict__ x, const float* __restrict__ g,
                            const float* __restrict__ be,
                            const float* __restrict__ Wi, const float* __restrict__ Wo,
                            const float* __restrict__ Wx,
                            __hip_bfloat16* __restrict__ xn,
                            __hip_bfloat16* __restrict__ Ti, __hip_bfloat16* __restrict__ To,
                            __hip_bfloat16* __restrict__ Tx) {
    __shared__ float tile[64][65];
    __shared__ float red[8];
    int bid = blockIdx.x;
    int tid = threadIdx.x;
    if (bid < NROWS) {
        // LayerNorm row
        int row = bid;
        const float* xr = x + (size_t)row * DM;
        float v0 = xr[tid], v1 = xr[tid + 256];
        float s = v0 + v1, sq = v0 * v0 + v1 * v1;
        #pragma unroll
        for (int o = 1; o < 64; o <<= 1) {
            s  += __shfl_xor(s, o);
            sq += __shfl_xor(sq, o);
        }
        int w = tid >> 6;
        if ((tid & 63) == 0) { red[w] = s; red[4 + w] = sq; }
        __syncthreads();
        float ts = red[0] + red[1] + red[2] + red[3];
        float tq = red[4] + red[5] + red[6] + red[7];
        float mu  = ts * (1.f / DM);
        float var = tq * (1.f / DM) - mu * mu;
        float inv = rsqrtf(var + 1e-5f);
        __hip_bfloat16* o0 = xn + (size_t)row * DM;
        o0[tid]       = __float2bfloat16((v0 - mu) * inv * g[tid]       + be[tid]);
        o0[tid + 256] = __float2bfloat16((v1 - mu) * inv * g[tid + 256] + be[tid + 256]);
        return;
    }
    int b2 = bid - NROWS;
    const float* in; __hip_bfloat16* out; int R, Cc, bx, by;
    if (b2 < 256)      { in = Wi; out = Ti; R = DM; Cc = 2 * DI; bx = b2 & 31; by = b2 >> 5; }
    else if (b2 < 384) { int b3 = b2 - 256; in = Wo; out = To; R = DI; Cc = DM;   bx = b3 & 7; by = b3 >> 3; }
    else               { int b3 = b2 - 384; in = Wx; out = Tx; R = DI; Cc = XDBW; bx = b3 % 3; by = b3 / 3; }
    int r0 = by * 64, c0 = bx * 64;
    #pragma unroll
    for (int i = tid; i < 4096; i += 256) {
        int r = i >> 6, c = i & 63;
        tile[r][c] = (r0 + r < R && c0 + c < Cc) ? in[(size_t)(r0 + r) * Cc + c0 + c] : 0.f;
    }
    __syncthreads();
    #pragma unroll
    for (int i = tid; i < 4096; i += 256) {
        int c = i >> 6, r = i & 63;
        if (r0 + r < R && c0 + c < Cc)
            out[(size_t)(c0 + c) * R + r0 + r] = __float2bfloat16(tile[r][c]);
    }
}

// ---------------- in_proj GEMM 128x128 tile, 512 thr; writes bf16 x-half / z-half ------
__global__ __launch_bounds__(512) void gemm_inproj(const __hip_bfloat16* __restrict__ A,
                                                   const __hip_bfloat16* __restrict__ Bt,
                                                   __hip_bfloat16* __restrict__ xh,
                                                   __hip_bfloat16* __restrict__ zh,
                                                   int M, int N, int K) {
    __shared__ __hip_bfloat16 As[128 * 32];
    __shared__ __hip_bfloat16 Bs[128 * 32];
    const int tid  = threadIdx.x;
    const int wave = tid >> 6, lane = tid & 63;
    const int m0 = blockIdx.y * 128, n0 = blockIdx.x * 128;
    const int wm = (wave >> 2) * 64, wn = (wave & 3) * 32;

    floatx4 acc[4][2] = {};

    const int arow16 = lane & 15;
    const int kgrp   = lane >> 4;

    for (int k0 = 0; k0 < K; k0 += 32) {
        {
            int i   = tid;                 // 0..511
            int row = i >> 2, seg = i & 3;
            const __hip_bfloat16* gA = A  + (size_t)(m0 + row) * K + k0 + seg * 8;
            const __hip_bfloat16* gB = Bt + (size_t)(n0 + row) * K + k0 + seg * 8;
            __hip_bfloat16* lA = As + (size_t)(wave * 64) * 8;
            __hip_bfloat16* lB = Bs + (size_t)(wave * 64) * 8;
            __builtin_amdgcn_global_load_lds(
                (const __attribute__((address_space(1))) void*)gA,
                (__attribute__((address_space(3))) void*)lA, 16, 0, 0);
            __builtin_amdgcn_global_load_lds(
                (const __attribute__((address_space(1))) void*)gB,
                (__attribute__((address_space(3))) void*)lB, 16, 0, 0);
        }
        __syncthreads();

        const shortx8* Asv = (const shortx8*)As;
        const shortx8* Bsv = (const shortx8*)Bs;
        shortx8 a[4], b[2];
        #pragma unroll
        for (int i = 0; i < 4; ++i)
            a[i] = Asv[(wm + i * 16 + arow16) * 4 + kgrp];
        #pragma unroll
        for (int j = 0; j < 2; ++j)
            b[j] = Bsv[(wn + j * 16 + arow16) * 4 + kgrp];
        #pragma unroll
        for (int i = 0; i < 4; ++i)
            #pragma unroll
            for (int j = 0; j < 2; ++j)
                acc[i][j] = __builtin_amdgcn_mfma_f32_16x16x32_bf16(a[i], b[j], acc[i][j], 0, 0, 0);
        __syncthreads();
    }

    const int drow = (lane >> 4) * 4;
    const int dcol = lane & 15;
    const bool isz = (n0 >= DI);
    __hip_bfloat16* dst = isz ? zh : xh;
    const int coloff = isz ? DI : 0;
    #pragma unroll
    for (int i = 0; i < 4; ++i)
        #pragma unroll
        for (int j = 0; j < 2; ++j) {
            int rowb = m0 + wm + i * 16 + drow;
            int col  = n0 + wn + j * 16 + dcol - coloff;
            #pragma unroll
            for (int r = 0; r < 4; ++r)
                dst[(size_t)(rowb + r) * DI + col] = __float2bfloat16(acc[i][j][r]);
        }
}

// ---------------- bf16 MFMA GEMM 64x64 tile, 512 thr, in-block split-K ----------------
template<bool RES>
__global__ __launch_bounds__(512) void gemm64_sk(const __hip_bfloat16* __restrict__ A,
                                                 const __hip_bfloat16* __restrict__ Bt,
                                                 const float* __restrict__ Res,
                                                 float* __restrict__ C,
                                                 int M, int N, int K) {
    __shared__ __hip_bfloat16 As[2][64 * 32];
    __shared__ __hip_bfloat16 Bs[2][64 * 32];
    __shared__ float red[256 * 17];
    const int tid  = threadIdx.x;
    const int wave = tid >> 6, lane = tid & 63;
    const int g = wave >> 2, w2 = wave & 3;
    const int m0 = blockIdx.y * 64, n0 = blockIdx.x * 64;
    const int wm = (w2 >> 1) * 32, wn = (w2 & 1) * 32;

    floatx4 acc[2][2] = {};

    const int arow16 = lane & 15;
    const int kgrp   = lane >> 4;
    const int kbeg   = g * (K / 2);

    for (int kk = 0; kk < K / 2; kk += 32) {
        int k0 = kbeg + kk;
        {
            int i   = w2 * 64 + lane;
            int row = i >> 2, seg = i & 3;
            int brow = n0 + row; if (brow >= N) brow = N - 1;
            const __hip_bfloat16* gA = A  + (size_t)(m0 + row) * K + k0 + seg * 8;
            const __hip_bfloat16* gB = Bt + (size_t)brow * K + k0 + seg * 8;
            __hip_bfloat16* lA = As[g] + (size_t)(w2 * 64) * 8;
            __hip_bfloat16* lB = Bs[g] + (size_t)(w2 * 64) * 8;
            __builtin_amdgcn_global_load_lds(
                (const __attribute__((address_space(1))) void*)gA,
                (__attribute__((address_space(3))) void*)lA, 16, 0, 0);
            __builtin_amdgcn_global_load_lds(
                (const __attribute__((address_space(1))) void*)gB,
                (__attribute__((address_space(3))) void*)lB, 16, 0, 0);
        }
        __syncthreads();

        const shortx8* Asv = (const shortx8*)As[g];
        const shortx8* Bsv = (const shortx8*)Bs[g];
        shortx8 a[2], b[2];
        #pragma unroll
        for (int i = 0; i < 2; ++i)
            a[i] = Asv[(wm + i * 16 + arow16) * 4 + kgrp];
        #pragma unroll
        for (int j = 0; j < 2; ++j)
            b[j] = Bsv[(wn + j * 16 + arow16) * 4 + kgrp];
        #pragma unroll
        for (int i = 0; i < 2; ++i)
            #pragma unroll
            for (int j = 0; j < 2; ++j)
                acc[i][j] = __builtin_amdgcn_mfma_f32_16x16x32_bf16(a[i], b[j], acc[i][j], 0, 0, 0);
        __syncthreads();
    }

    int rbase = (w2 * 64 + lane) * 17;
    if (g == 1) {
        #pragma unroll
        for (int i = 0; i < 2; ++i)
            #pragma unroll
            for (int j = 0; j < 2; ++j)
                *(float4*)&red[rbase + (i * 2 + j) * 4] =
                    make_float4(acc[i][j][0], acc[i][j][1], acc[i][j][2], acc[i][j][3]);
    }
    __syncthreads();
    if (g == 0) {
        const int drow = (lane >> 4) * 4;
        const int dcol = lane & 15;
        #pragma unroll
        for (int i = 0; i < 2; ++i)
            #pragma unroll
            for (int j = 0; j < 2; ++j) {
                float4 part = *(const float4*)&red[rbase + (i * 2 + j) * 4];
                int rowb = m0 + wm + i * 16 + drow;
                int col  = n0 + wn + j * 16 + dcol;
                if (col < N) {
                    #pragma unroll
                    for (int r = 0; r < 4; ++r) {
                        size_t idx = (size_t)(rowb + r) * N + col;
                        float v = acc[i][j][r] + (&part.x)[r];
                        if (RES) v += Res[idx];
                        C[idx] = v;
                    }
                }
            }
    }
}

// ---------------- Tiled conv + silu + transposes ----------------
__global__ __launch_bounds__(256) void conv_tile(const __hip_bfloat16* __restrict__ xh,
                                                 const __hip_bfloat16* __restrict__ zh,
                                                 const float* __restrict__ cw,
                                                 const float* __restrict__ cb,
                                                 __hip_bfloat16* __restrict__ xcv_bf,
                                                 __hip_bfloat16* __restrict__ xcvT,
                                                 __hip_bfloat16* __restrict__ zgT) {
    __shared__ float xt[67][68];
    __shared__ float tb[64][65];    // conv+silu result [t][d]
    __shared__ float tb2[64][65];   // silu(z) [t][d]
    int t0 = blockIdx.x * 64, d0 = blockIdx.y * 64, b = blockIdx.z;
    int tid = threadIdx.x;
    size_t rowbase = (size_t)b * Lseq;

    for (int i = tid; i < 67 * 16; i += 256) {
        int r = i >> 4, j = i & 15;
        int t = t0 - 3 + r;
        float4 v4 = make_float4(0.f, 0.f, 0.f, 0.f);
        if (t >= 0) {
            ushort4 u = *(const ushort4*)&xh[(rowbase + t) * DI + d0 + j * 4];
            v4 = make_float4(bf2f(u.x), bf2f(u.y), bf2f(u.z), bf2f(u.w));
        }
        *(float4*)&xt[r][j * 4] = v4;
    }
    for (int i = tid; i < 64 * 16; i += 256) {
        int r = i >> 4, j = i & 15;
        ushort4 u = *(const ushort4*)&zh[(rowbase + t0 + r) * DI + d0 + j * 4];
        tb2[r][j * 4 + 0] = silu_f(bf2f(u.x));
        tb2[r][j * 4 + 1] = silu_f(bf2f(u.y));
        tb2[r][j * 4 + 2] = silu_f(bf2f(u.z));
        tb2[r][j * 4 + 3] = silu_f(bf2f(u.w));
    }
    __syncthreads();

    {
        int d = tid & 63, tg = tid >> 6;
        float4 cwv = *(const float4*)&cw[(d0 + d) * 4];
        float cbv = cb[d0 + d];
        #pragma unroll
        for (int i = 0; i < 16; ++i) {
            int t = tg * 16 + i;
            float acc = cbv;
            #pragma unroll
            for (int k = 0; k < 4; ++k) acc += xt[t + k][d] * (&cwv.x)[k];
            float v = silu_f(acc);
            tb[t][d] = v;
            xcv_bf[(rowbase + t0 + t) * DI + d0 + d] = __float2bfloat16(v);
        }
    }
    __syncthreads();

    {
        int t2 = tid & 63, dg2 = tid >> 6;
        #pragma unroll
        for (int i = 0; i < 16; ++i) {
            int d = dg2 * 16 + i;
            size_t orow = ((size_t)(b * DI + d0 + d)) * Lseq + t0 + t2;
            xcvT[orow] = __float2bfloat16(tb[t2][d]);
            zgT[orow]  = __float2bfloat16(tb2[t2][d]);
        }
    }
}

// ============ Chunked scan, phase 1 (δ computed in-register from xdb) ============
__global__ __launch_bounds__(512) void scan_chunk1(
        const __hip_bfloat16* __restrict__ xcvT, const float* __restrict__ xdb,
        const float* __restrict__ A_log, const float* __restrict__ Wdt,
        const float* __restrict__ bdt,
        float* __restrict__ hend, float* __restrict__ dsum) {
    __shared__ float Bsh[64][68];
    __shared__ float xsh[8][64];

    int blk = blockIdx.x;
    int dg  = blk & (DI / 8 - 1);   // 0..127
    int bc  = blk >> 7;             // b*NC + c
    int c = bc & (NC - 1), b = bc >> 4;
    int tid = threadIdx.x, w = tid >> 6, lane = tid & 63;
    int d = dg * 8 + w;
    int r0 = b * Lseq + c * CH;

    // stage B (cols 32..95 of xdb), float4
    #pragma unroll
    for (int k = 0; k < 2; ++k) {
        int idx = tid + k * 512;
        int row = idx >> 4, j4 = idx & 15;
        float4 v = *(const float4*)&xdb[(size_t)(r0 + row) * XDBW + RNK + j4 * 4];
        *(float4*)&Bsh[row][j4 * 4] = v;
    }
    xsh[w][lane] = bf2f(((const unsigned short*)xcvT)[((size_t)(b * DI + d)) * Lseq + c * CH + lane]);
    __syncthreads();

    float vd  = delta_of(xdb, (size_t)(r0 + lane), Wdt, bdt, d);  // delta for t=lane
    float vpx = vd * xsh[w][lane];
    float a = -__expf(A_log[d * DS + lane]);
    float h = 0.f;
    #pragma unroll 16
    for (int t = 0; t < CH; ++t) {
        float dt_ = rdl(vd, t);
        float px  = rdl(vpx, t);
        h = h * __expf(dt_ * a) + px * Bsh[t][lane];
    }
    float S = vd;
    #pragma unroll
    for (int o = 1; o < 64; o <<= 1) S += __shfl_xor(S, o);
    size_t base = ((size_t)bc * DI + d) * 64;
    hend[base + lane] = h;
    if (lane == 0) dsum[(size_t)bc * DI + d] = S;
}

// ============ Chunked scan, phase 2: stitch across chunks ============
__global__ __launch_bounds__(256) void scan_stitch(
        const float* __restrict__ hend, const float* __restrict__ dsum,
        const float* __restrict__ A_log, float* __restrict__ hstart) {
    int idx = blockIdx.x * 4 + (threadIdx.x >> 6);   // b*DI + d
    int lane = threadIdx.x & 63;
    int b = idx >> 10, d = idx & (DI - 1);
    float a = -__expf(A_log[d * DS + lane]);
    float h = 0.f;
    #pragma unroll
    for (int c = 0; c < NC; ++c) {
        size_t base = ((size_t)(b * NC + c) * DI + d) * 64;
        hstart[base + lane] = h;
        float he = hend[base + lane];
        float S  = dsum[(size_t)(b * NC + c) * DI + d];
        h = he + __expf(a * S) * h;
    }
}

// ============ Chunked scan, phase 3 (δ in-register; emits gated y_row bf16) ============
__global__ __launch_bounds__(512) void scan_chunk2(
        const __hip_bfloat16* __restrict__ xcvT, const float* __restrict__ xdb,
        const __hip_bfloat16* __restrict__ zgT,
        const float* __restrict__ A_log, const float* __restrict__ Dp,
        const float* __restrict__ Wdt, const float* __restrict__ bdt,
        const float* __restrict__ hstart, __hip_bfloat16* __restrict__ y_row) {
    __shared__ unsigned int BCsh[64][65];  // [t][s] = (C & 0xFFFF0000) | (B >> 16)
    __shared__ float xsh[8][64];
    __shared__ float zsh[8][64];
    __shared__ float P[8][8 * 65];

    int blk = blockIdx.x;
    int dg  = blk & (DI / 8 - 1);
    int bc  = blk >> 7;
    int c = bc & (NC - 1), b = bc >> 4;
    int tid = threadIdx.x, w = tid >> 6, lane = tid & 63;
    int d = dg * 8 + w;
    int r0 = b * Lseq + c * CH;

    // stage BC packed
    #pragma unroll
    for (int k = 0; k < 2; ++k) {
        int i = tid + k * 512;
        int t = i >> 4, sg = i & 15;
        const float* rowp = &xdb[(size_t)(r0 + t) * XDBW + RNK];
        float4 bv = *(const float4*)&rowp[sg * 4];
        float4 cv = *(const float4*)&rowp[DS + sg * 4];
        uint4 pk;
        #pragma unroll
        for (int j = 0; j < 4; ++j) {
            unsigned int bb = __float_as_uint((&bv.x)[j]);
            unsigned int cc2 = __float_as_uint((&cv.x)[j]);
            (&pk.x)[j] = (cc2 & 0xFFFF0000u) | (bb >> 16);
        }
        *(uint4*)&BCsh[t][sg * 4] = pk;
    }
    {
        size_t trow = ((size_t)(b * DI + d)) * Lseq + c * CH + lane;
        xsh[w][lane] = bf2f(((const unsigned short*)xcvT)[trow]);
        zsh[w][lane] = bf2f(((const unsigned short*)zgT)[trow]);   // already silu'd
    }
    __syncthreads();

    float vd  = delta_of(xdb, (size_t)(r0 + lane), Wdt, bdt, d);
    float vpx = vd * xsh[w][lane];
    float a  = -__expf(A_log[d * DS + lane]);
    float Dv = Dp[d];
    float h = hstart[((size_t)bc * DI + d) * 64 + lane];
    float* Pw = P[w];
    float yreg = 0.f;
    const int tr = lane & 7, q = lane >> 3;

    #pragma unroll
    for (int t8 = 0; t8 < 8; ++t8) {
        #pragma unroll
        for (int tt = 0; tt < 8; ++tt) {
            int t = t8 * 8 + tt;
            unsigned int bcp = BCsh[t][lane];
            float Bt = __uint_as_float(bcp << 16);
            float Ct = __uint_as_float(bcp & 0xFFFF0000u);
            float dt_ = rdl(vd, t);
            float px  = rdl(vpx, t);
            h = h * __expf(dt_ * a) + px * Bt;
            Pw[tt * 65 + lane] = h * Ct;
        }
        float sacc = 0.f;
        #pragma unroll
        for (int j = 0; j < 8; ++j) sacc += Pw[tr * 65 + q * 8 + j];
        sacc += __shfl_xor(sacc, 8);
        sacc += __shfl_xor(sacc, 16);
        sacc += __shfl_xor(sacc, 32);
        if (q == t8) yreg = sacc;
    }

    float yv = (yreg + xsh[w][lane] * Dv) * zsh[w][lane];

    // block-wide transpose (reuse P as T[64][9]) -> y_row[t][d] bf16
    __syncthreads();
    float* T = (float*)P;
    T[lane * 9 + w] = yv;
    __syncthreads();
    {
        int t = tid >> 3, dd = tid & 7;
        float v = T[t * 9 + dd];
        y_row[(size_t)(r0 + t) * DI + dg * 8 + dd] = __float2bfloat16(v);
    }
}

extern "C" void kernel_launch(void* const* d_in, const int* in_sizes, int n_in,
                              void* d_out, int out_size, void* d_ws, size_t ws_size,
                              hipStream_t stream) {
    const float* frames = (const float*)d_in[0];
    const float* gamma  = (const float*)d_in[1];
    const float* beta   = (const float*)d_in[2];
    const float* W_in   = (const float*)d_in[3];
    const float* conv_w = (const float*)d_in[4];
    const float* conv_b = (const float*)d_in[5];
    const float* W_x    = (const float*)d_in[6];
    const float* W_dt   = (const float*)d_in[7];
    const float* b_dt   = (const float*)d_in[8];
    const float* A_log  = (const float*)d_in[9];
    const float* Dp     = (const float*)d_in[10];
    const float* W_out  = (const float*)d_in[11];
    float* out = (float*)d_out;

    // workspace carve-up (bytes)
    char* ws = (char*)d_ws;
    __hip_bfloat16* xn_bf  = (__hip_bfloat16*)ws; ws += (size_t)NROWS * DM * 2;
    __hip_bfloat16* Wt_in  = (__hip_bfloat16*)ws; ws += (size_t)(2 * DI) * DM * 2;
    __hip_bfloat16* Wt_out = (__hip_bfloat16*)ws; ws += (size_t)DM * DI * 2;
    __hip_bfloat16* Wt_x   = (__hip_bfloat16*)ws; ws += (size_t)XDBW * DI * 2;
    __hip_bfloat16* y_row  = (__hip_bfloat16*)ws; ws += (size_t)NROWS * DI * 2;
    __hip_bfloat16* xcv_bf = (__hip_bfloat16*)ws; ws += (size_t)NROWS * DI * 2;
    __hip_bfloat16* xh     = (__hip_bfloat16*)ws; ws += (size_t)NROWS * DI * 2;
    __hip_bfloat16* zh     = (__hip_bfloat16*)ws; ws += (size_t)NROWS * DI * 2;
    __hip_bfloat16* xcvT   = (__hip_bfloat16*)ws; ws += (size_t)NROWS * DI * 2;
    __hip_bfloat16* zgT    = (__hip_bfloat16*)ws; ws += (size_t)NROWS * DI * 2;
    float* xdb    = (float*)ws;  ws += (size_t)NROWS * XDBW * 4;
    float* hend   = (float*)ws;  ws += (size_t)Bn * NC * DI * 64 * 4;
    float* hstart = (float*)ws;  ws += (size_t)Bn * NC * DI * 64 * 4;
    float* dsum   = (float*)ws;  ws += (size_t)Bn * NC * DI * 4;

    // fused LN + weight transposes
    prep_kernel<<<NROWS + 432, 256, 0, stream>>>(frames, gamma, beta, W_in, W_out, W_x,
                                                 xn_bf, Wt_in, Wt_out, Wt_x);

    // in_proj -> bf16 x-half / z-half
    gemm_inproj<<<dim3(2 * DI / 128, NROWS / 128), 512, 0, stream>>>(
        xn_bf, Wt_in, xh, zh, NROWS, 2 * DI, DM);

    // conv + silu + transposes
    conv_tile<<<dim3(Lseq / 64, DI / 64, Bn), 256, 0, stream>>>(
        xh, zh, conv_w, conv_b, xcv_bf, xcvT, zgT);

    // xdb = xcv @ W_x  (M=2048, N=160, K=1024)
    gemm64_sk<false><<<dim3((XDBW + 63) / 64, NROWS / 64), 512, 0, stream>>>(
        xcv_bf, Wt_x, nullptr, xdb, NROWS, XDBW, DI);

    // chunked selective scan (delta computed in-kernel)
    scan_chunk1<<<Bn * NC * (DI / 8), 512, 0, stream>>>(xcvT, xdb, A_log, W_dt, b_dt, hend, dsum);
    scan_stitch<<<Bn * DI / 4, 256, 0, stream>>>(hend, dsum, A_log, hstart);
    scan_chunk2<<<Bn * NC * (DI / 8), 512, 0, stream>>>(xcvT, xdb, zgT, A_log, Dp, W_dt, b_dt,
                                                        hstart, y_row);

    // out_proj: out = y_row @ W_out + frames
    gemm64_sk<true><<<dim3(DM / 64, NROWS / 64), 512, 0, stream>>>(
        y_row, Wt_out, frames, out, NROWS, DM, DI);
}

// Round 13
// 232.385 us; speedup vs baseline: 1.1037x; 1.1037x over previous
//
#include <hip/hip_runtime.h>
#include <hip/hip_bf16.h>
#include <math.h>

// Problem constants
constexpr int Bn     = 2;
constexpr int Lseq   = 1024;
constexpr int DM     = 512;    // d_model
constexpr int DI     = 1024;   // d_inner
constexpr int DS     = 64;     // d_state
constexpr int RNK    = 32;     // dt_rank
constexpr int NROWS  = Bn * Lseq;  // 2048
constexpr int XDBW   = RNK + 2 * DS; // 160
constexpr int CH     = 64;     // scan chunk length
constexpr int NC     = Lseq / CH;  // 16 chunks

typedef __attribute__((ext_vector_type(4))) float floatx4;
typedef __attribute__((ext_vector_type(8))) short shortx8;

__device__ __forceinline__ float silu_f(float v) {
    return v / (1.f + __expf(-v));
}

__device__ __forceinline__ float rdl(float v, int l) {
    return __int_as_float(__builtin_amdgcn_readlane(__float_as_int(v), l));
}

__device__ __forceinline__ float bf2f(unsigned short u) {
    return __uint_as_float((unsigned)u << 16);
}

// ---------------- Fused prep: LN (blocks 0..2047) + 3 weight transposes (2048..2479) ----
__global__ void prep_kernel(const float* __restrict__ x, const float* __restrict__ g,
                            const float* __restrict__ be,
                            const float* __restrict__ Wi, const float* __restrict__ Wo,
                            const float* __restrict__ Wx,
                            __hip_bfloat16* __restrict__ xn,
                            __hip_bfloat16* __restrict__ Ti, __hip_bfloat16* __restrict__ To,
                            __hip_bfloat16* __restrict__ Tx) {
    __shared__ float tile[64][65];
    __shared__ float red[8];
    int bid = blockIdx.x;
    int tid = threadIdx.x;
    if (bid < NROWS) {
        int row = bid;
        const float* xr = x + (size_t)row * DM;
        float v0 = xr[tid], v1 = xr[tid + 256];
        float s = v0 + v1, sq = v0 * v0 + v1 * v1;
        #pragma unroll
        for (int o = 1; o < 64; o <<= 1) {
            s  += __shfl_xor(s, o);
            sq += __shfl_xor(sq, o);
        }
        int w = tid >> 6;
        if ((tid & 63) == 0) { red[w] = s; red[4 + w] = sq; }
        __syncthreads();
        float ts = red[0] + red[1] + red[2] + red[3];
        float tq = red[4] + red[5] + red[6] + red[7];
        float mu  = ts * (1.f / DM);
        float var = tq * (1.f / DM) - mu * mu;
        float inv = rsqrtf(var + 1e-5f);
        __hip_bfloat16* o0 = xn + (size_t)row * DM;
        o0[tid]       = __float2bfloat16((v0 - mu) * inv * g[tid]       + be[tid]);
        o0[tid + 256] = __float2bfloat16((v1 - mu) * inv * g[tid + 256] + be[tid + 256]);
        return;
    }
    int b2 = bid - NROWS;
    const float* in; __hip_bfloat16* out; int R, Cc, bx, by;
    if (b2 < 256)      { in = Wi; out = Ti; R = DM; Cc = 2 * DI; bx = b2 & 31; by = b2 >> 5; }
    else if (b2 < 384) { int b3 = b2 - 256; in = Wo; out = To; R = DI; Cc = DM;   bx = b3 & 7; by = b3 >> 3; }
    else               { int b3 = b2 - 384; in = Wx; out = Tx; R = DI; Cc = XDBW; bx = b3 % 3; by = b3 / 3; }
    int r0 = by * 64, c0 = bx * 64;
    #pragma unroll
    for (int i = tid; i < 4096; i += 256) {
        int r = i >> 6, c = i & 63;
        tile[r][c] = (r0 + r < R && c0 + c < Cc) ? in[(size_t)(r0 + r) * Cc + c0 + c] : 0.f;
    }
    __syncthreads();
    #pragma unroll
    for (int i = tid; i < 4096; i += 256) {
        int c = i >> 6, r = i & 63;
        if (r0 + r < R && c0 + c < Cc)
            out[(size_t)(c0 + c) * R + r0 + r] = __float2bfloat16(tile[r][c]);
    }
}

// ---------------- in_proj GEMM 128x128 tile, 512 thr; writes bf16 x-half / z-half ------
__global__ __launch_bounds__(512) void gemm_inproj(const __hip_bfloat16* __restrict__ A,
                                                   const __hip_bfloat16* __restrict__ Bt,
                                                   __hip_bfloat16* __restrict__ xh,
                                                   __hip_bfloat16* __restrict__ zh,
                                                   int M, int N, int K) {
    __shared__ __hip_bfloat16 As[128 * 32];
    __shared__ __hip_bfloat16 Bs[128 * 32];
    const int tid  = threadIdx.x;
    const int wave = tid >> 6, lane = tid & 63;
    const int m0 = blockIdx.y * 128, n0 = blockIdx.x * 128;
    const int wm = (wave >> 2) * 64, wn = (wave & 3) * 32;

    floatx4 acc[4][2] = {};

    const int arow16 = lane & 15;
    const int kgrp   = lane >> 4;

    for (int k0 = 0; k0 < K; k0 += 32) {
        {
            int i   = tid;                 // 0..511
            int row = i >> 2, seg = i & 3;
            const __hip_bfloat16* gA = A  + (size_t)(m0 + row) * K + k0 + seg * 8;
            const __hip_bfloat16* gB = Bt + (size_t)(n0 + row) * K + k0 + seg * 8;
            __hip_bfloat16* lA = As + (size_t)(wave * 64) * 8;
            __hip_bfloat16* lB = Bs + (size_t)(wave * 64) * 8;
            __builtin_amdgcn_global_load_lds(
                (const __attribute__((address_space(1))) void*)gA,
                (__attribute__((address_space(3))) void*)lA, 16, 0, 0);
            __builtin_amdgcn_global_load_lds(
                (const __attribute__((address_space(1))) void*)gB,
                (__attribute__((address_space(3))) void*)lB, 16, 0, 0);
        }
        __syncthreads();

        const shortx8* Asv = (const shortx8*)As;
        const shortx8* Bsv = (const shortx8*)Bs;
        shortx8 a[4], b[2];
        #pragma unroll
        for (int i = 0; i < 4; ++i)
            a[i] = Asv[(wm + i * 16 + arow16) * 4 + kgrp];
        #pragma unroll
        for (int j = 0; j < 2; ++j)
            b[j] = Bsv[(wn + j * 16 + arow16) * 4 + kgrp];
        #pragma unroll
        for (int i = 0; i < 4; ++i)
            #pragma unroll
            for (int j = 0; j < 2; ++j)
                acc[i][j] = __builtin_amdgcn_mfma_f32_16x16x32_bf16(a[i], b[j], acc[i][j], 0, 0, 0);
        __syncthreads();
    }

    const int drow = (lane >> 4) * 4;
    const int dcol = lane & 15;
    const bool isz = (n0 >= DI);
    __hip_bfloat16* dst = isz ? zh : xh;
    const int coloff = isz ? DI : 0;
    #pragma unroll
    for (int i = 0; i < 4; ++i)
        #pragma unroll
        for (int j = 0; j < 2; ++j) {
            int rowb = m0 + wm + i * 16 + drow;
            int col  = n0 + wn + j * 16 + dcol - coloff;
            #pragma unroll
            for (int r = 0; r < 4; ++r)
                dst[(size_t)(rowb + r) * DI + col] = __float2bfloat16(acc[i][j][r]);
        }
}

// ---------------- bf16 MFMA GEMM 64x64 tile, 512 thr, in-block split-K ----------------
template<bool RES>
__global__ __launch_bounds__(512) void gemm64_sk(const __hip_bfloat16* __restrict__ A,
                                                 const __hip_bfloat16* __restrict__ Bt,
                                                 const float* __restrict__ Res,
                                                 float* __restrict__ C,
                                                 int M, int N, int K) {
    __shared__ __hip_bfloat16 As[2][64 * 32];
    __shared__ __hip_bfloat16 Bs[2][64 * 32];
    __shared__ float red[256 * 17];
    const int tid  = threadIdx.x;
    const int wave = tid >> 6, lane = tid & 63;
    const int g = wave >> 2, w2 = wave & 3;
    const int m0 = blockIdx.y * 64, n0 = blockIdx.x * 64;
    const int wm = (w2 >> 1) * 32, wn = (w2 & 1) * 32;

    floatx4 acc[2][2] = {};

    const int arow16 = lane & 15;
    const int kgrp   = lane >> 4;
    const int kbeg   = g * (K / 2);

    for (int kk = 0; kk < K / 2; kk += 32) {
        int k0 = kbeg + kk;
        {
            int i   = w2 * 64 + lane;
            int row = i >> 2, seg = i & 3;
            int brow = n0 + row; if (brow >= N) brow = N - 1;
            const __hip_bfloat16* gA = A  + (size_t)(m0 + row) * K + k0 + seg * 8;
            const __hip_bfloat16* gB = Bt + (size_t)brow * K + k0 + seg * 8;
            __hip_bfloat16* lA = As[g] + (size_t)(w2 * 64) * 8;
            __hip_bfloat16* lB = Bs[g] + (size_t)(w2 * 64) * 8;
            __builtin_amdgcn_global_load_lds(
                (const __attribute__((address_space(1))) void*)gA,
                (__attribute__((address_space(3))) void*)lA, 16, 0, 0);
            __builtin_amdgcn_global_load_lds(
                (const __attribute__((address_space(1))) void*)gB,
                (__attribute__((address_space(3))) void*)lB, 16, 0, 0);
        }
        __syncthreads();

        const shortx8* Asv = (const shortx8*)As[g];
        const shortx8* Bsv = (const shortx8*)Bs[g];
        shortx8 a[2], b[2];
        #pragma unroll
        for (int i = 0; i < 2; ++i)
            a[i] = Asv[(wm + i * 16 + arow16) * 4 + kgrp];
        #pragma unroll
        for (int j = 0; j < 2; ++j)
            b[j] = Bsv[(wn + j * 16 + arow16) * 4 + kgrp];
        #pragma unroll
        for (int i = 0; i < 2; ++i)
            #pragma unroll
            for (int j = 0; j < 2; ++j)
                acc[i][j] = __builtin_amdgcn_mfma_f32_16x16x32_bf16(a[i], b[j], acc[i][j], 0, 0, 0);
        __syncthreads();
    }

    int rbase = (w2 * 64 + lane) * 17;
    if (g == 1) {
        #pragma unroll
        for (int i = 0; i < 2; ++i)
            #pragma unroll
            for (int j = 0; j < 2; ++j)
                *(float4*)&red[rbase + (i * 2 + j) * 4] =
                    make_float4(acc[i][j][0], acc[i][j][1], acc[i][j][2], acc[i][j][3]);
    }
    __syncthreads();
    if (g == 0) {
        const int drow = (lane >> 4) * 4;
        const int dcol = lane & 15;
        #pragma unroll
        for (int i = 0; i < 2; ++i)
            #pragma unroll
            for (int j = 0; j < 2; ++j) {
                float4 part = *(const float4*)&red[rbase + (i * 2 + j) * 4];
                int rowb = m0 + wm + i * 16 + drow;
                int col  = n0 + wn + j * 16 + dcol;
                if (col < N) {
                    #pragma unroll
                    for (int r = 0; r < 4; ++r) {
                        size_t idx = (size_t)(rowb + r) * N + col;
                        float v = acc[i][j][r] + (&part.x)[r];
                        if (RES) v += Res[idx];
                        C[idx] = v;
                    }
                }
            }
    }
}

// ---------------- Tiled conv + silu + transposes ----------------
__global__ __launch_bounds__(256) void conv_tile(const __hip_bfloat16* __restrict__ xh,
                                                 const __hip_bfloat16* __restrict__ zh,
                                                 const float* __restrict__ cw,
                                                 const float* __restrict__ cb,
                                                 __hip_bfloat16* __restrict__ xcv_bf,
                                                 __hip_bfloat16* __restrict__ xcvT,
                                                 __hip_bfloat16* __restrict__ zgT) {
    __shared__ float xt[67][68];
    __shared__ float tb[64][65];    // conv+silu result [t][d]
    __shared__ float tb2[64][65];   // silu(z) [t][d]
    int t0 = blockIdx.x * 64, d0 = blockIdx.y * 64, b = blockIdx.z;
    int tid = threadIdx.x;
    size_t rowbase = (size_t)b * Lseq;

    for (int i = tid; i < 67 * 16; i += 256) {
        int r = i >> 4, j = i & 15;
        int t = t0 - 3 + r;
        float4 v4 = make_float4(0.f, 0.f, 0.f, 0.f);
        if (t >= 0) {
            ushort4 u = *(const ushort4*)&xh[(rowbase + t) * DI + d0 + j * 4];
            v4 = make_float4(bf2f(u.x), bf2f(u.y), bf2f(u.z), bf2f(u.w));
        }
        *(float4*)&xt[r][j * 4] = v4;
    }
    for (int i = tid; i < 64 * 16; i += 256) {
        int r = i >> 4, j = i & 15;
        ushort4 u = *(const ushort4*)&zh[(rowbase + t0 + r) * DI + d0 + j * 4];
        tb2[r][j * 4 + 0] = silu_f(bf2f(u.x));
        tb2[r][j * 4 + 1] = silu_f(bf2f(u.y));
        tb2[r][j * 4 + 2] = silu_f(bf2f(u.z));
        tb2[r][j * 4 + 3] = silu_f(bf2f(u.w));
    }
    __syncthreads();

    {
        int d = tid & 63, tg = tid >> 6;
        float4 cwv = *(const float4*)&cw[(d0 + d) * 4];
        float cbv = cb[d0 + d];
        #pragma unroll
        for (int i = 0; i < 16; ++i) {
            int t = tg * 16 + i;
            float acc = cbv;
            #pragma unroll
            for (int k = 0; k < 4; ++k) acc += xt[t + k][d] * (&cwv.x)[k];
            float v = silu_f(acc);
            tb[t][d] = v;
            xcv_bf[(rowbase + t0 + t) * DI + d0 + d] = __float2bfloat16(v);
        }
    }
    __syncthreads();

    {
        int t2 = tid & 63, dg2 = tid >> 6;
        #pragma unroll
        for (int i = 0; i < 16; ++i) {
            int d = dg2 * 16 + i;
            size_t orow = ((size_t)(b * DI + d0 + d)) * Lseq + t0 + t2;
            xcvT[orow] = __float2bfloat16(tb[t2][d]);
            zgT[orow]  = __float2bfloat16(tb2[t2][d]);
        }
    }
}

// ---------------- delta = softplus(dt @ W_dt + b_dt) ----------------
__global__ void delta_kernel(const float* __restrict__ xdb, const float* __restrict__ Wdt,
                             const float* __restrict__ bdt, float* __restrict__ delta) {
    int row = blockIdx.y;
    int d = blockIdx.x * 256 + threadIdx.x;
    __shared__ float dtv[RNK];
    if (threadIdx.x < RNK) dtv[threadIdx.x] = xdb[(size_t)row * XDBW + threadIdx.x];
    __syncthreads();
    float acc = bdt[d];
    #pragma unroll
    for (int r = 0; r < RNK; ++r) acc += dtv[r] * Wdt[(size_t)r * DI + d];
    float sp = (acc > 20.f) ? acc : log1pf(__expf(acc));
    delta[(size_t)row * DI + d] = sp;
}

// ============ Chunked scan, phase 1: 2 d-channels per wave ============
// Block covers 16 d (waves w -> d = dbase+w and dbase+8+w); B-tile shared by both.
// dsh/xsh stride 65: write banks (dd+t)%32 distinct (free), read 2-way.
__global__ __launch_bounds__(512) void scan_chunk1(
        const float* __restrict__ delta, const __hip_bfloat16* __restrict__ xcvT,
        const float* __restrict__ xdb, const float* __restrict__ A_log,
        float* __restrict__ hend, float* __restrict__ dsum) {
    __shared__ float Bsh[64][68];
    __shared__ float dsh[16][65];
    __shared__ float xsh[16][65];

    int blk = blockIdx.x;
    int dg  = blk & 63;             // DI/16 = 64
    int bc  = blk >> 6;             // b*NC + c
    int c = bc & (NC - 1), b = bc >> 4;
    int tid = threadIdx.x, w = tid >> 6, lane = tid & 63;
    int dbase = dg * 16;
    int r0 = b * Lseq + c * CH;

    // stage B (cols 32..95 of xdb), float4
    #pragma unroll
    for (int k = 0; k < 2; ++k) {
        int idx = tid + k * 512;
        int row = idx >> 4, j4 = idx & 15;
        float4 v = *(const float4*)&xdb[(size_t)(r0 + row) * XDBW + RNK + j4 * 4];
        *(float4*)&Bsh[row][j4 * 4] = v;
    }
    // stage delta [dd][t]
    #pragma unroll
    for (int k = 0; k < 2; ++k) {
        int i = tid + k * 512;
        int dd = i & 15, t = i >> 4;
        dsh[dd][t] = delta[(size_t)(r0 + t) * DI + dbase + dd];
    }
    // stage x from transposed bf16: wave-contiguous d-rows
    #pragma unroll
    for (int k = 0; k < 2; ++k) {
        int i = tid + k * 512;
        int dd = i >> 6, t = i & 63;
        xsh[dd][t] = bf2f(((const unsigned short*)xcvT)[
            ((size_t)(b * DI + dbase + dd)) * Lseq + c * CH + t]);
    }
    __syncthreads();

    int d0 = dbase + w, d1 = dbase + 8 + w;
    float a0 = -__expf(A_log[d0 * DS + lane]);
    float a1 = -__expf(A_log[d1 * DS + lane]);
    float vd0 = dsh[w][lane],     vd1 = dsh[8 + w][lane];
    float vpx0 = vd0 * xsh[w][lane], vpx1 = vd1 * xsh[8 + w][lane];
    float h0 = 0.f, h1 = 0.f;
    #pragma unroll 16
    for (int t = 0; t < CH; ++t) {
        float Bt = Bsh[t][lane];
        h0 = h0 * __expf(rdl(vd0, t) * a0) + rdl(vpx0, t) * Bt;
        h1 = h1 * __expf(rdl(vd1, t) * a1) + rdl(vpx1, t) * Bt;
    }
    float S0 = vd0, S1 = vd1;
    #pragma unroll
    for (int o = 1; o < 64; o <<= 1) {
        S0 += __shfl_xor(S0, o);
        S1 += __shfl_xor(S1, o);
    }
    size_t cb = (size_t)bc * DI;
    hend[(cb + d0) * 64 + lane] = h0;
    hend[(cb + d1) * 64 + lane] = h1;
    if (lane == 0) {
        dsum[cb + d0] = S0;
        dsum[cb + d1] = S1;
    }
}

// ============ Chunked scan, phase 2: stitch across chunks ============
__global__ __launch_bounds__(256) void scan_stitch(
        const float* __restrict__ hend, const float* __restrict__ dsum,
        const float* __restrict__ A_log, float* __restrict__ hstart) {
    int idx = blockIdx.x * 4 + (threadIdx.x >> 6);   // b*DI + d
    int lane = threadIdx.x & 63;
    int b = idx >> 10, d = idx & (DI - 1);
    float a = -__expf(A_log[d * DS + lane]);
    float h = 0.f;
    #pragma unroll
    for (int c = 0; c < NC; ++c) {
        size_t base = ((size_t)(b * NC + c) * DI + d) * 64;
        hstart[base + lane] = h;
        float he = hend[base + lane];
        float S  = dsum[(size_t)(b * NC + c) * DI + d];
        h = he + __expf(a * S) * h;
    }
}

// ============ Chunked scan, phase 3: recompute with h_start, emit gated y_row bf16 ======
__global__ __launch_bounds__(512) void scan_chunk2(
        const float* __restrict__ delta, const __hip_bfloat16* __restrict__ xcvT,
        const float* __restrict__ xdb, const __hip_bfloat16* __restrict__ zgT,
        const float* __restrict__ A_log, const float* __restrict__ Dp,
        const float* __restrict__ hstart, __hip_bfloat16* __restrict__ y_row) {
    __shared__ unsigned int BCsh[64][65];  // [t][s] = (C & 0xFFFF0000) | (B >> 16)
    __shared__ float dsh[8][64];
    __shared__ float xsh[8][64];
    __shared__ float zsh[8][64];
    __shared__ float P[8][8 * 65];

    int blk = blockIdx.x;
    int dg  = blk & (DI / 8 - 1);
    int bc  = blk >> 7;
    int c = bc & (NC - 1), b = bc >> 4;
    int tid = threadIdx.x, w = tid >> 6, lane = tid & 63;
    int d = dg * 8 + w;
    int r0 = b * Lseq + c * CH;

    // stage BC packed
    #pragma unroll
    for (int k = 0; k < 2; ++k) {
        int i = tid + k * 512;
        int t = i >> 4, sg = i & 15;
        const float* rowp = &xdb[(size_t)(r0 + t) * XDBW + RNK];
        float4 bv = *(const float4*)&rowp[sg * 4];
        float4 cv = *(const float4*)&rowp[DS + sg * 4];
        uint4 pk;
        #pragma unroll
        for (int j = 0; j < 4; ++j) {
            unsigned int bb = __float_as_uint((&bv.x)[j]);
            unsigned int cc2 = __float_as_uint((&cv.x)[j]);
            (&pk.x)[j] = (cc2 & 0xFFFF0000u) | (bb >> 16);
        }
        *(uint4*)&BCsh[t][sg * 4] = pk;
    }
    {
        int t = tid >> 3, ww = tid & 7;
        dsh[ww][t] = delta[(size_t)(r0 + t) * DI + dg * 8 + ww];
        size_t trow = ((size_t)(b * DI + d)) * Lseq + c * CH + lane;
        xsh[w][lane] = bf2f(((const unsigned short*)xcvT)[trow]);
        zsh[w][lane] = bf2f(((const unsigned short*)zgT)[trow]);   // already silu'd
    }
    __syncthreads();

    float a  = -__expf(A_log[d * DS + lane]);
    float Dv = Dp[d];
    float vd  = dsh[w][lane];
    float vpx = vd * xsh[w][lane];
    float h = hstart[((size_t)bc * DI + d) * 64 + lane];
    float* Pw = P[w];
    float yreg = 0.f;
    const int tr = lane & 7, q = lane >> 3;

    #pragma unroll
    for (int t8 = 0; t8 < 8; ++t8) {
        #pragma unroll
        for (int tt = 0; tt < 8; ++tt) {
            int t = t8 * 8 + tt;
            unsigned int bcp = BCsh[t][lane];
            float Bt = __uint_as_float(bcp << 16);
            float Ct = __uint_as_float(bcp & 0xFFFF0000u);
            float dt_ = rdl(vd, t);
            float px  = rdl(vpx, t);
            h = h * __expf(dt_ * a) + px * Bt;
            Pw[tt * 65 + lane] = h * Ct;
        }
        float sacc = 0.f;
        #pragma unroll
        for (int j = 0; j < 8; ++j) sacc += Pw[tr * 65 + q * 8 + j];
        sacc += __shfl_xor(sacc, 8);
        sacc += __shfl_xor(sacc, 16);
        sacc += __shfl_xor(sacc, 32);
        if (q == t8) yreg = sacc;
    }

    float yv = (yreg + xsh[w][lane] * Dv) * zsh[w][lane];

    // block-wide transpose (reuse P as T[64][9]) -> y_row[t][d] bf16
    __syncthreads();
    float* T = (float*)P;
    T[lane * 9 + w] = yv;
    __syncthreads();
    {
        int t = tid >> 3, dd = tid & 7;
        float v = T[t * 9 + dd];
        y_row[(size_t)(r0 + t) * DI + dg * 8 + dd] = __float2bfloat16(v);
    }
}

extern "C" void kernel_launch(void* const* d_in, const int* in_sizes, int n_in,
                              void* d_out, int out_size, void* d_ws, size_t ws_size,
                              hipStream_t stream) {
    const float* frames = (const float*)d_in[0];
    const float* gamma  = (const float*)d_in[1];
    const float* beta   = (const float*)d_in[2];
    const float* W_in   = (const float*)d_in[3];
    const float* conv_w = (const float*)d_in[4];
    const float* conv_b = (const float*)d_in[5];
    const float* W_x    = (const float*)d_in[6];
    const float* W_dt   = (const float*)d_in[7];
    const float* b_dt   = (const float*)d_in[8];
    const float* A_log  = (const float*)d_in[9];
    const float* Dp     = (const float*)d_in[10];
    const float* W_out  = (const float*)d_in[11];
    float* out = (float*)d_out;

    // workspace carve-up (bytes)
    char* ws = (char*)d_ws;
    __hip_bfloat16* xn_bf  = (__hip_bfloat16*)ws; ws += (size_t)NROWS * DM * 2;
    __hip_bfloat16* Wt_in  = (__hip_bfloat16*)ws; ws += (size_t)(2 * DI) * DM * 2;
    __hip_bfloat16* Wt_out = (__hip_bfloat16*)ws; ws += (size_t)DM * DI * 2;
    __hip_bfloat16* Wt_x   = (__hip_bfloat16*)ws; ws += (size_t)XDBW * DI * 2;
    __hip_bfloat16* y_row  = (__hip_bfloat16*)ws; ws += (size_t)NROWS * DI * 2;
    __hip_bfloat16* xcv_bf = (__hip_bfloat16*)ws; ws += (size_t)NROWS * DI * 2;
    __hip_bfloat16* xh     = (__hip_bfloat16*)ws; ws += (size_t)NROWS * DI * 2;
    __hip_bfloat16* zh     = (__hip_bfloat16*)ws; ws += (size_t)NROWS * DI * 2;
    __hip_bfloat16* xcvT   = (__hip_bfloat16*)ws; ws += (size_t)NROWS * DI * 2;
    __hip_bfloat16* zgT    = (__hip_bfloat16*)ws; ws += (size_t)NROWS * DI * 2;
    float* xdb    = (float*)ws;  ws += (size_t)NROWS * XDBW * 4;
    float* delta  = (float*)ws;  ws += (size_t)NROWS * DI * 4;
    float* hend   = (float*)ws;  ws += (size_t)Bn * NC * DI * 64 * 4;
    float* hstart = (float*)ws;  ws += (size_t)Bn * NC * DI * 64 * 4;
    float* dsum   = (float*)ws;  ws += (size_t)Bn * NC * DI * 4;

    // fused LN + weight transposes
    prep_kernel<<<NROWS + 432, 256, 0, stream>>>(frames, gamma, beta, W_in, W_out, W_x,
                                                 xn_bf, Wt_in, Wt_out, Wt_x);

    // in_proj -> bf16 x-half / z-half
    gemm_inproj<<<dim3(2 * DI / 128, NROWS / 128), 512, 0, stream>>>(
        xn_bf, Wt_in, xh, zh, NROWS, 2 * DI, DM);

    // conv + silu + transposes
    conv_tile<<<dim3(Lseq / 64, DI / 64, Bn), 256, 0, stream>>>(
        xh, zh, conv_w, conv_b, xcv_bf, xcvT, zgT);

    // xdb = xcv @ W_x  (M=2048, N=160, K=1024)
    gemm64_sk<false><<<dim3((XDBW + 63) / 64, NROWS / 64), 512, 0, stream>>>(
        xcv_bf, Wt_x, nullptr, xdb, NROWS, XDBW, DI);

    delta_kernel<<<dim3(DI / 256, NROWS), 256, 0, stream>>>(xdb, W_dt, b_dt, delta);

    // chunked selective scan (chunk1: 2 d-channels/wave)
    scan_chunk1<<<Bn * NC * (DI / 16), 512, 0, stream>>>(delta, xcvT, xdb, A_log, hend, dsum);
    scan_stitch<<<Bn * DI / 4, 256, 0, stream>>>(hend, dsum, A_log, hstart);
    scan_chunk2<<<Bn * NC * (DI / 8), 512, 0, stream>>>(delta, xcvT, xdb, zgT, A_log, Dp,
                                                        hstart, y_row);

    // out_proj: out = y_row @ W_out + frames
    gemm64_sk<true><<<dim3(DM / 64, NROWS / 64), 512, 0, stream>>>(
        y_row, Wt_out, frames, out, NROWS, DM, DI);
}

// Round 14
// 230.122 us; speedup vs baseline: 1.1146x; 1.0098x over previous
//
#include <hip/hip_runtime.h>
#include <hip/hip_bf16.h>
#include <math.h>

// Problem constants
constexpr int Bn     = 2;
constexpr int Lseq   = 1024;
constexpr int DM     = 512;    // d_model
constexpr int DI     = 1024;   // d_inner
constexpr int DS     = 64;     // d_state
constexpr int RNK    = 32;     // dt_rank
constexpr int NROWS  = Bn * Lseq;  // 2048
constexpr int XDBW   = RNK + 2 * DS; // 160
constexpr int CH     = 64;     // scan chunk length
constexpr int NC     = Lseq / CH;  // 16 chunks

typedef __attribute__((ext_vector_type(4))) float floatx4;
typedef __attribute__((ext_vector_type(8))) short shortx8;

__device__ __forceinline__ float silu_f(float v) {
    return v / (1.f + __expf(-v));
}

__device__ __forceinline__ float rdl(float v, int l) {
    return __int_as_float(__builtin_amdgcn_readlane(__float_as_int(v), l));
}

__device__ __forceinline__ float bf2f(unsigned short u) {
    return __uint_as_float((unsigned)u << 16);
}

// ---------------- Fused prep: LN (blocks 0..2047) + 3 weight transposes (2048..2479) ----
__global__ void prep_kernel(const float* __restrict__ x, const float* __restrict__ g,
                            const float* __restrict__ be,
                            const float* __restrict__ Wi, const float* __restrict__ Wo,
                            const float* __restrict__ Wx,
                            __hip_bfloat16* __restrict__ xn,
                            __hip_bfloat16* __restrict__ Ti, __hip_bfloat16* __restrict__ To,
                            __hip_bfloat16* __restrict__ Tx) {
    __shared__ float tile[64][65];
    __shared__ float red[8];
    int bid = blockIdx.x;
    int tid = threadIdx.x;
    if (bid < NROWS) {
        int row = bid;
        const float* xr = x + (size_t)row * DM;
        float v0 = xr[tid], v1 = xr[tid + 256];
        float s = v0 + v1, sq = v0 * v0 + v1 * v1;
        #pragma unroll
        for (int o = 1; o < 64; o <<= 1) {
            s  += __shfl_xor(s, o);
            sq += __shfl_xor(sq, o);
        }
        int w = tid >> 6;
        if ((tid & 63) == 0) { red[w] = s; red[4 + w] = sq; }
        __syncthreads();
        float ts = red[0] + red[1] + red[2] + red[3];
        float tq = red[4] + red[5] + red[6] + red[7];
        float mu  = ts * (1.f / DM);
        float var = tq * (1.f / DM) - mu * mu;
        float inv = rsqrtf(var + 1e-5f);
        __hip_bfloat16* o0 = xn + (size_t)row * DM;
        o0[tid]       = __float2bfloat16((v0 - mu) * inv * g[tid]       + be[tid]);
        o0[tid + 256] = __float2bfloat16((v1 - mu) * inv * g[tid + 256] + be[tid + 256]);
        return;
    }
    int b2 = bid - NROWS;
    const float* in; __hip_bfloat16* out; int R, Cc, bx, by;
    if (b2 < 256)      { in = Wi; out = Ti; R = DM; Cc = 2 * DI; bx = b2 & 31; by = b2 >> 5; }
    else if (b2 < 384) { int b3 = b2 - 256; in = Wo; out = To; R = DI; Cc = DM;   bx = b3 & 7; by = b3 >> 3; }
    else               { int b3 = b2 - 384; in = Wx; out = Tx; R = DI; Cc = XDBW; bx = b3 % 3; by = b3 / 3; }
    int r0 = by * 64, c0 = bx * 64;
    #pragma unroll
    for (int i = tid; i < 4096; i += 256) {
        int r = i >> 6, c = i & 63;
        tile[r][c] = (r0 + r < R && c0 + c < Cc) ? in[(size_t)(r0 + r) * Cc + c0 + c] : 0.f;
    }
    __syncthreads();
    #pragma unroll
    for (int i = tid; i < 4096; i += 256) {
        int c = i >> 6, r = i & 63;
        if (r0 + r < R && c0 + c < Cc)
            out[(size_t)(c0 + c) * R + r0 + r] = __float2bfloat16(tile[r][c]);
    }
}

// ---------------- in_proj GEMM 128x128 tile, 512 thr, BK=64 (2 stacked 32-K panels) -----
// Panel h occupies LDS elems [h*4096, h*4096+4096): layout row*32 + seg*8 — identical
// bank pattern to the proven BK=32 staging. 8 K-iters for K=512 (half the barriers).
__global__ __launch_bounds__(512) void gemm_inproj(const __hip_bfloat16* __restrict__ A,
                                                   const __hip_bfloat16* __restrict__ Bt,
                                                   __hip_bfloat16* __restrict__ xh,
                                                   __hip_bfloat16* __restrict__ zh,
                                                   int M, int N, int K) {
    __shared__ __hip_bfloat16 As[128 * 64];
    __shared__ __hip_bfloat16 Bs[128 * 64];
    const int tid  = threadIdx.x;
    const int wave = tid >> 6, lane = tid & 63;
    const int m0 = blockIdx.y * 128, n0 = blockIdx.x * 128;
    const int wm = (wave >> 2) * 64, wn = (wave & 3) * 32;

    floatx4 acc[4][2] = {};

    const int arow16 = lane & 15;
    const int kgrp   = lane >> 4;

    for (int k0 = 0; k0 < K; k0 += 64) {
        #pragma unroll
        for (int p = 0; p < 2; ++p) {
            int j = tid + p * 512;            // 0..1023 chunk index
            int h = j >> 9, rs = j & 511;
            int row = rs >> 2, seg = rs & 3;
            const __hip_bfloat16* gA = A  + (size_t)(m0 + row) * K + k0 + h * 32 + seg * 8;
            const __hip_bfloat16* gB = Bt + (size_t)(n0 + row) * K + k0 + h * 32 + seg * 8;
            __hip_bfloat16* lA = As + (size_t)(wave * 64 + p * 512) * 8;
            __hip_bfloat16* lB = Bs + (size_t)(wave * 64 + p * 512) * 8;
            __builtin_amdgcn_global_load_lds(
                (const __attribute__((address_space(1))) void*)gA,
                (__attribute__((address_space(3))) void*)lA, 16, 0, 0);
            __builtin_amdgcn_global_load_lds(
                (const __attribute__((address_space(1))) void*)gB,
                (__attribute__((address_space(3))) void*)lB, 16, 0, 0);
        }
        __syncthreads();

        const shortx8* Asv = (const shortx8*)As;
        const shortx8* Bsv = (const shortx8*)Bs;
        #pragma unroll
        for (int h = 0; h < 2; ++h) {
            shortx8 a[4], b[2];
            #pragma unroll
            for (int i = 0; i < 4; ++i)
                a[i] = Asv[h * 512 + (wm + i * 16 + arow16) * 4 + kgrp];
            #pragma unroll
            for (int j = 0; j < 2; ++j)
                b[j] = Bsv[h * 512 + (wn + j * 16 + arow16) * 4 + kgrp];
            #pragma unroll
            for (int i = 0; i < 4; ++i)
                #pragma unroll
                for (int j = 0; j < 2; ++j)
                    acc[i][j] = __builtin_amdgcn_mfma_f32_16x16x32_bf16(a[i], b[j], acc[i][j], 0, 0, 0);
        }
        __syncthreads();
    }

    const int drow = (lane >> 4) * 4;
    const int dcol = lane & 15;
    const bool isz = (n0 >= DI);
    __hip_bfloat16* dst = isz ? zh : xh;
    const int coloff = isz ? DI : 0;
    #pragma unroll
    for (int i = 0; i < 4; ++i)
        #pragma unroll
        for (int j = 0; j < 2; ++j) {
            int rowb = m0 + wm + i * 16 + drow;
            int col  = n0 + wn + j * 16 + dcol - coloff;
            #pragma unroll
            for (int r = 0; r < 4; ++r)
                dst[(size_t)(rowb + r) * DI + col] = __float2bfloat16(acc[i][j][r]);
        }
}

// ---------------- bf16 MFMA GEMM 64x64 tile, 512 thr, split-K, BK=64 (2 panels) ---------
template<bool RES>
__global__ __launch_bounds__(512) void gemm64_sk(const __hip_bfloat16* __restrict__ A,
                                                 const __hip_bfloat16* __restrict__ Bt,
                                                 const float* __restrict__ Res,
                                                 float* __restrict__ C,
                                                 int M, int N, int K) {
    __shared__ __hip_bfloat16 As[2][64 * 64];
    __shared__ __hip_bfloat16 Bs[2][64 * 64];
    __shared__ float red[256 * 17];
    const int tid  = threadIdx.x;
    const int wave = tid >> 6, lane = tid & 63;
    const int g = wave >> 2, w2 = wave & 3;
    const int m0 = blockIdx.y * 64, n0 = blockIdx.x * 64;
    const int wm = (w2 >> 1) * 32, wn = (w2 & 1) * 32;

    floatx4 acc[2][2] = {};

    const int arow16 = lane & 15;
    const int kgrp   = lane >> 4;
    const int kbeg   = g * (K / 2);

    for (int kk = 0; kk < K / 2; kk += 64) {
        int k0 = kbeg + kk;
        #pragma unroll
        for (int p = 0; p < 2; ++p) {
            int j = (w2 * 64 + lane) + p * 256;   // 0..511 chunk index within group
            int h = j >> 8, rs = j & 255;
            int row = rs >> 2, seg = rs & 3;
            int brow = n0 + row; if (brow >= N) brow = N - 1;
            const __hip_bfloat16* gA = A  + (size_t)(m0 + row) * K + k0 + h * 32 + seg * 8;
            const __hip_bfloat16* gB = Bt + (size_t)brow * K + k0 + h * 32 + seg * 8;
            __hip_bfloat16* lA = As[g] + (size_t)(w2 * 64 + p * 256) * 8;
            __hip_bfloat16* lB = Bs[g] + (size_t)(w2 * 64 + p * 256) * 8;
            __builtin_amdgcn_global_load_lds(
                (const __attribute__((address_space(1))) void*)gA,
                (__attribute__((address_space(3))) void*)lA, 16, 0, 0);
            __builtin_amdgcn_global_load_lds(
                (const __attribute__((address_space(1))) void*)gB,
                (__attribute__((address_space(3))) void*)lB, 16, 0, 0);
        }
        __syncthreads();

        const shortx8* Asv = (const shortx8*)As[g];
        const shortx8* Bsv = (const shortx8*)Bs[g];
        #pragma unroll
        for (int h = 0; h < 2; ++h) {
            shortx8 a[2], b[2];
            #pragma unroll
            for (int i = 0; i < 2; ++i)
                a[i] = Asv[h * 256 + (wm + i * 16 + arow16) * 4 + kgrp];
            #pragma unroll
            for (int j = 0; j < 2; ++j)
                b[j] = Bsv[h * 256 + (wn + j * 16 + arow16) * 4 + kgrp];
            #pragma unroll
            for (int i = 0; i < 2; ++i)
                #pragma unroll
                for (int j = 0; j < 2; ++j)
                    acc[i][j] = __builtin_amdgcn_mfma_f32_16x16x32_bf16(a[i], b[j], acc[i][j], 0, 0, 0);
        }
        __syncthreads();
    }

    int rbase = (w2 * 64 + lane) * 17;
    if (g == 1) {
        #pragma unroll
        for (int i = 0; i < 2; ++i)
            #pragma unroll
            for (int j = 0; j < 2; ++j)
                *(float4*)&red[rbase + (i * 2 + j) * 4] =
                    make_float4(acc[i][j][0], acc[i][j][1], acc[i][j][2], acc[i][j][3]);
    }
    __syncthreads();
    if (g == 0) {
        const int drow = (lane >> 4) * 4;
        const int dcol = lane & 15;
        #pragma unroll
        for (int i = 0; i < 2; ++i)
            #pragma unroll
            for (int j = 0; j < 2; ++j) {
                float4 part = *(const float4*)&red[rbase + (i * 2 + j) * 4];
                int rowb = m0 + wm + i * 16 + drow;
                int col  = n0 + wn + j * 16 + dcol;
                if (col < N) {
                    #pragma unroll
                    for (int r = 0; r < 4; ++r) {
                        size_t idx = (size_t)(rowb + r) * N + col;
                        float v = acc[i][j][r] + (&part.x)[r];
                        if (RES) v += Res[idx];
                        C[idx] = v;
                    }
                }
            }
    }
}

// ---------------- Tiled conv + silu + transposes ----------------
__global__ __launch_bounds__(256) void conv_tile(const __hip_bfloat16* __restrict__ xh,
                                                 const __hip_bfloat16* __restrict__ zh,
                                                 const float* __restrict__ cw,
                                                 const float* __restrict__ cb,
                                                 __hip_bfloat16* __restrict__ xcv_bf,
                                                 __hip_bfloat16* __restrict__ xcvT,
                                                 __hip_bfloat16* __restrict__ zgT) {
    __shared__ float xt[67][68];
    __shared__ float tb[64][65];    // conv+silu result [t][d]
    __shared__ float tb2[64][65];   // silu(z) [t][d]
    int t0 = blockIdx.x * 64, d0 = blockIdx.y * 64, b = blockIdx.z;
    int tid = threadIdx.x;
    size_t rowbase = (size_t)b * Lseq;

    for (int i = tid; i < 67 * 16; i += 256) {
        int r = i >> 4, j = i & 15;
        int t = t0 - 3 + r;
        float4 v4 = make_float4(0.f, 0.f, 0.f, 0.f);
        if (t >= 0) {
            ushort4 u = *(const ushort4*)&xh[(rowbase + t) * DI + d0 + j * 4];
            v4 = make_float4(bf2f(u.x), bf2f(u.y), bf2f(u.z), bf2f(u.w));
        }
        *(float4*)&xt[r][j * 4] = v4;
    }
    for (int i = tid; i < 64 * 16; i += 256) {
        int r = i >> 4, j = i & 15;
        ushort4 u = *(const ushort4*)&zh[(rowbase + t0 + r) * DI + d0 + j * 4];
        tb2[r][j * 4 + 0] = silu_f(bf2f(u.x));
        tb2[r][j * 4 + 1] = silu_f(bf2f(u.y));
        tb2[r][j * 4 + 2] = silu_f(bf2f(u.z));
        tb2[r][j * 4 + 3] = silu_f(bf2f(u.w));
    }
    __syncthreads();

    {
        int d = tid & 63, tg = tid >> 6;
        float4 cwv = *(const float4*)&cw[(d0 + d) * 4];
        float cbv = cb[d0 + d];
        #pragma unroll
        for (int i = 0; i < 16; ++i) {
            int t = tg * 16 + i;
            float acc = cbv;
            #pragma unroll
            for (int k = 0; k < 4; ++k) acc += xt[t + k][d] * (&cwv.x)[k];
            float v = silu_f(acc);
            tb[t][d] = v;
            xcv_bf[(rowbase + t0 + t) * DI + d0 + d] = __float2bfloat16(v);
        }
    }
    __syncthreads();

    {
        int t2 = tid & 63, dg2 = tid >> 6;
        #pragma unroll
        for (int i = 0; i < 16; ++i) {
            int d = dg2 * 16 + i;
            size_t orow = ((size_t)(b * DI + d0 + d)) * Lseq + t0 + t2;
            xcvT[orow] = __float2bfloat16(tb[t2][d]);
            zgT[orow]  = __float2bfloat16(tb2[t2][d]);
        }
    }
}

// ---------------- delta = softplus(dt @ W_dt + b_dt) ----------------
__global__ void delta_kernel(const float* __restrict__ xdb, const float* __restrict__ Wdt,
                             const float* __restrict__ bdt, float* __restrict__ delta) {
    int row = blockIdx.y;
    int d = blockIdx.x * 256 + threadIdx.x;
    __shared__ float dtv[RNK];
    if (threadIdx.x < RNK) dtv[threadIdx.x] = xdb[(size_t)row * XDBW + threadIdx.x];
    __syncthreads();
    float acc = bdt[d];
    #pragma unroll
    for (int r = 0; r < RNK; ++r) acc += dtv[r] * Wdt[(size_t)r * DI + d];
    float sp = (acc > 20.f) ? acc : log1pf(__expf(acc));
    delta[(size_t)row * DI + d] = sp;
}

// ============ Chunked scan, phase 1: 2 d-channels per wave ============
__global__ __launch_bounds__(512) void scan_chunk1(
        const float* __restrict__ delta, const __hip_bfloat16* __restrict__ xcvT,
        const float* __restrict__ xdb, const float* __restrict__ A_log,
        float* __restrict__ hend, float* __restrict__ dsum) {
    __shared__ float Bsh[64][68];
    __shared__ float dsh[16][65];
    __shared__ float xsh[16][65];

    int blk = blockIdx.x;
    int dg  = blk & 63;             // DI/16 = 64
    int bc  = blk >> 6;             // b*NC + c
    int c = bc & (NC - 1), b = bc >> 4;
    int tid = threadIdx.x, w = tid >> 6, lane = tid & 63;
    int dbase = dg * 16;
    int r0 = b * Lseq + c * CH;

    #pragma unroll
    for (int k = 0; k < 2; ++k) {
        int idx = tid + k * 512;
        int row = idx >> 4, j4 = idx & 15;
        float4 v = *(const float4*)&xdb[(size_t)(r0 + row) * XDBW + RNK + j4 * 4];
        *(float4*)&Bsh[row][j4 * 4] = v;
    }
    #pragma unroll
    for (int k = 0; k < 2; ++k) {
        int i = tid + k * 512;
        int dd = i & 15, t = i >> 4;
        dsh[dd][t] = delta[(size_t)(r0 + t) * DI + dbase + dd];
    }
    #pragma unroll
    for (int k = 0; k < 2; ++k) {
        int i = tid + k * 512;
        int dd = i >> 6, t = i & 63;
        xsh[dd][t] = bf2f(((const unsigned short*)xcvT)[
            ((size_t)(b * DI + dbase + dd)) * Lseq + c * CH + t]);
    }
    __syncthreads();

    int d0 = dbase + w, d1 = dbase + 8 + w;
    float a0 = -__expf(A_log[d0 * DS + lane]);
    float a1 = -__expf(A_log[d1 * DS + lane]);
    float vd0 = dsh[w][lane],     vd1 = dsh[8 + w][lane];
    float vpx0 = vd0 * xsh[w][lane], vpx1 = vd1 * xsh[8 + w][lane];
    float h0 = 0.f, h1 = 0.f;
    #pragma unroll 16
    for (int t = 0; t < CH; ++t) {
        float Bt = Bsh[t][lane];
        h0 = h0 * __expf(rdl(vd0, t) * a0) + rdl(vpx0, t) * Bt;
        h1 = h1 * __expf(rdl(vd1, t) * a1) + rdl(vpx1, t) * Bt;
    }
    float S0 = vd0, S1 = vd1;
    #pragma unroll
    for (int o = 1; o < 64; o <<= 1) {
        S0 += __shfl_xor(S0, o);
        S1 += __shfl_xor(S1, o);
    }
    size_t cb = (size_t)bc * DI;
    hend[(cb + d0) * 64 + lane] = h0;
    hend[(cb + d1) * 64 + lane] = h1;
    if (lane == 0) {
        dsum[cb + d0] = S0;
        dsum[cb + d1] = S1;
    }
}

// ============ Chunked scan, phase 2: stitch across chunks ============
__global__ __launch_bounds__(256) void scan_stitch(
        const float* __restrict__ hend, const float* __restrict__ dsum,
        const float* __restrict__ A_log, float* __restrict__ hstart) {
    int idx = blockIdx.x * 4 + (threadIdx.x >> 6);   // b*DI + d
    int lane = threadIdx.x & 63;
    int b = idx >> 10, d = idx & (DI - 1);
    float a = -__expf(A_log[d * DS + lane]);
    float h = 0.f;
    #pragma unroll
    for (int c = 0; c < NC; ++c) {
        size_t base = ((size_t)(b * NC + c) * DI + d) * 64;
        hstart[base + lane] = h;
        float he = hend[base + lane];
        float S  = dsum[(size_t)(b * NC + c) * DI + d];
        h = he + __expf(a * S) * h;
    }
}

// ============ Chunked scan, phase 3: recompute with h_start, emit gated y_row bf16 ======
__global__ __launch_bounds__(512) void scan_chunk2(
        const float* __restrict__ delta, const __hip_bfloat16* __restrict__ xcvT,
        const float* __restrict__ xdb, const __hip_bfloat16* __restrict__ zgT,
        const float* __restrict__ A_log, const float* __restrict__ Dp,
        const float* __restrict__ hstart, __hip_bfloat16* __restrict__ y_row) {
    __shared__ unsigned int BCsh[64][65];  // [t][s] = (C & 0xFFFF0000) | (B >> 16)
    __shared__ float dsh[8][64];
    __shared__ float xsh[8][64];
    __shared__ float zsh[8][64];
    __shared__ float P[8][8 * 65];

    int blk = blockIdx.x;
    int dg  = blk & (DI / 8 - 1);
    int bc  = blk >> 7;
    int c = bc & (NC - 1), b = bc >> 4;
    int tid = threadIdx.x, w = tid >> 6, lane = tid & 63;
    int d = dg * 8 + w;
    int r0 = b * Lseq + c * CH;

    #pragma unroll
    for (int k = 0; k < 2; ++k) {
        int i = tid + k * 512;
        int t = i >> 4, sg = i & 15;
        const float* rowp = &xdb[(size_t)(r0 + t) * XDBW + RNK];
        float4 bv = *(const float4*)&rowp[sg * 4];
        float4 cv = *(const float4*)&rowp[DS + sg * 4];
        uint4 pk;
        #pragma unroll
        for (int j = 0; j < 4; ++j) {
            unsigned int bb = __float_as_uint((&bv.x)[j]);
            unsigned int cc2 = __float_as_uint((&cv.x)[j]);
            (&pk.x)[j] = (cc2 & 0xFFFF0000u) | (bb >> 16);
        }
        *(uint4*)&BCsh[t][sg * 4] = pk;
    }
    {
        int t = tid >> 3, ww = tid & 7;
        dsh[ww][t] = delta[(size_t)(r0 + t) * DI + dg * 8 + ww];
        size_t trow = ((size_t)(b * DI + d)) * Lseq + c * CH + lane;
        xsh[w][lane] = bf2f(((const unsigned short*)xcvT)[trow]);
        zsh[w][lane] = bf2f(((const unsigned short*)zgT)[trow]);   // already silu'd
    }
    __syncthreads();

    float a  = -__expf(A_log[d * DS + lane]);
    float Dv = Dp[d];
    float vd  = dsh[w][lane];
    float vpx = vd * xsh[w][lane];
    float h = hstart[((size_t)bc * DI + d) * 64 + lane];
    float* Pw = P[w];
    float yreg = 0.f;
    const int tr = lane & 7, q = lane >> 3;

    #pragma unroll
    for (int t8 = 0; t8 < 8; ++t8) {
        #pragma unroll
        for (int tt = 0; tt < 8; ++tt) {
            int t = t8 * 8 + tt;
            unsigned int bcp = BCsh[t][lane];
            float Bt = __uint_as_float(bcp << 16);
            float Ct = __uint_as_float(bcp & 0xFFFF0000u);
            float dt_ = rdl(vd, t);
            float px  = rdl(vpx, t);
            h = h * __expf(dt_ * a) + px * Bt;
            Pw[tt * 65 + lane] = h * Ct;
        }
        float sacc = 0.f;
        #pragma unroll
        for (int j = 0; j < 8; ++j) sacc += Pw[tr * 65 + q * 8 + j];
        sacc += __shfl_xor(sacc, 8);
        sacc += __shfl_xor(sacc, 16);
        sacc += __shfl_xor(sacc, 32);
        if (q == t8) yreg = sacc;
    }

    float yv = (yreg + xsh[w][lane] * Dv) * zsh[w][lane];

    __syncthreads();
    float* T = (float*)P;
    T[lane * 9 + w] = yv;
    __syncthreads();
    {
        int t = tid >> 3, dd = tid & 7;
        float v = T[t * 9 + dd];
        y_row[(size_t)(r0 + t) * DI + dg * 8 + dd] = __float2bfloat16(v);
    }
}

extern "C" void kernel_launch(void* const* d_in, const int* in_sizes, int n_in,
                              void* d_out, int out_size, void* d_ws, size_t ws_size,
                              hipStream_t stream) {
    const float* frames = (const float*)d_in[0];
    const float* gamma  = (const float*)d_in[1];
    const float* beta   = (const float*)d_in[2];
    const float* W_in   = (const float*)d_in[3];
    const float* conv_w = (const float*)d_in[4];
    const float* conv_b = (const float*)d_in[5];
    const float* W_x    = (const float*)d_in[6];
    const float* W_dt   = (const float*)d_in[7];
    const float* b_dt   = (const float*)d_in[8];
    const float* A_log  = (const float*)d_in[9];
    const float* Dp     = (const float*)d_in[10];
    const float* W_out  = (const float*)d_in[11];
    float* out = (float*)d_out;

    // workspace carve-up (bytes)
    char* ws = (char*)d_ws;
    __hip_bfloat16* xn_bf  = (__hip_bfloat16*)ws; ws += (size_t)NROWS * DM * 2;
    __hip_bfloat16* Wt_in  = (__hip_bfloat16*)ws; ws += (size_t)(2 * DI) * DM * 2;
    __hip_bfloat16* Wt_out = (__hip_bfloat16*)ws; ws += (size_t)DM * DI * 2;
    __hip_bfloat16* Wt_x   = (__hip_bfloat16*)ws; ws += (size_t)XDBW * DI * 2;
    __hip_bfloat16* y_row  = (__hip_bfloat16*)ws; ws += (size_t)NROWS * DI * 2;
    __hip_bfloat16* xcv_bf = (__hip_bfloat16*)ws; ws += (size_t)NROWS * DI * 2;
    __hip_bfloat16* xh     = (__hip_bfloat16*)ws; ws += (size_t)NROWS * DI * 2;
    __hip_bfloat16* zh     = (__hip_bfloat16*)ws; ws += (size_t)NROWS * DI * 2;
    __hip_bfloat16* xcvT   = (__hip_bfloat16*)ws; ws += (size_t)NROWS * DI * 2;
    __hip_bfloat16* zgT    = (__hip_bfloat16*)ws; ws += (size_t)NROWS * DI * 2;
    float* xdb    = (float*)ws;  ws += (size_t)NROWS * XDBW * 4;
    float* delta  = (float*)ws;  ws += (size_t)NROWS * DI * 4;
    float* hend   = (float*)ws;  ws += (size_t)Bn * NC * DI * 64 * 4;
    float* hstart = (float*)ws;  ws += (size_t)Bn * NC * DI * 64 * 4;
    float* dsum   = (float*)ws;  ws += (size_t)Bn * NC * DI * 4;

    // fused LN + weight transposes
    prep_kernel<<<NROWS + 432, 256, 0, stream>>>(frames, gamma, beta, W_in, W_out, W_x,
                                                 xn_bf, Wt_in, Wt_out, Wt_x);

    // in_proj -> bf16 x-half / z-half (BK=64)
    gemm_inproj<<<dim3(2 * DI / 128, NROWS / 128), 512, 0, stream>>>(
        xn_bf, Wt_in, xh, zh, NROWS, 2 * DI, DM);

    // conv + silu + transposes
    conv_tile<<<dim3(Lseq / 64, DI / 64, Bn), 256, 0, stream>>>(
        xh, zh, conv_w, conv_b, xcv_bf, xcvT, zgT);

    // xdb = xcv @ W_x  (M=2048, N=160, K=1024, BK=64 split-K)
    gemm64_sk<false><<<dim3((XDBW + 63) / 64, NROWS / 64), 512, 0, stream>>>(
        xcv_bf, Wt_x, nullptr, xdb, NROWS, XDBW, DI);

    delta_kernel<<<dim3(DI / 256, NROWS), 256, 0, stream>>>(xdb, W_dt, b_dt, delta);

    // chunked selective scan (chunk1: 2 d-channels/wave)
    scan_chunk1<<<Bn * NC * (DI / 16), 512, 0, stream>>>(delta, xcvT, xdb, A_log, hend, dsum);
    scan_stitch<<<Bn * DI / 4, 256, 0, stream>>>(hend, dsum, A_log, hstart);
    scan_chunk2<<<Bn * NC * (DI / 8), 512, 0, stream>>>(delta, xcvT, xdb, zgT, A_log, Dp,
                                                        hstart, y_row);

    // out_proj: out = y_row @ W_out + frames (BK=64 split-K)
    gemm64_sk<true><<<dim3(DM / 64, NROWS / 64), 512, 0, stream>>>(
        y_row, Wt_out, frames, out, NROWS, DM, DI);
}

// Round 15
// 229.141 us; speedup vs baseline: 1.1194x; 1.0043x over previous
//
#include <hip/hip_runtime.h>
#include <hip/hip_bf16.h>
#include <math.h>

// Problem constants
constexpr int Bn     = 2;
constexpr int Lseq   = 1024;
constexpr int DM     = 512;    // d_model
constexpr int DI     = 1024;   // d_inner
constexpr int DS     = 64;     // d_state
constexpr int RNK    = 32;     // dt_rank
constexpr int NROWS  = Bn * Lseq;  // 2048
constexpr int XDBW   = RNK + 2 * DS; // 160
constexpr int CH     = 64;     // scan chunk length
constexpr int NC     = Lseq / CH;  // 16 chunks

typedef __attribute__((ext_vector_type(4))) float floatx4;
typedef __attribute__((ext_vector_type(8))) short shortx8;

__device__ __forceinline__ float silu_f(float v) {
    return v / (1.f + __expf(-v));
}

__device__ __forceinline__ float rdl(float v, int l) {
    return __int_as_float(__builtin_amdgcn_readlane(__float_as_int(v), l));
}

__device__ __forceinline__ float bf2f(unsigned short u) {
    return __uint_as_float((unsigned)u << 16);
}

// ---------------- Fused prep: LN (blocks 0..2047) + 3 weight transposes (2048..2479) ----
__global__ void prep_kernel(const float* __restrict__ x, const float* __restrict__ g,
                            const float* __restrict__ be,
                            const float* __restrict__ Wi, const float* __restrict__ Wo,
                            const float* __restrict__ Wx,
                            __hip_bfloat16* __restrict__ xn,
                            __hip_bfloat16* __restrict__ Ti, __hip_bfloat16* __restrict__ To,
                            __hip_bfloat16* __restrict__ Tx) {
    __shared__ float tile[64][65];
    __shared__ float red[8];
    int bid = blockIdx.x;
    int tid = threadIdx.x;
    if (bid < NROWS) {
        int row = bid;
        const float* xr = x + (size_t)row * DM;
        float v0 = xr[tid], v1 = xr[tid + 256];
        float s = v0 + v1, sq = v0 * v0 + v1 * v1;
        #pragma unroll
        for (int o = 1; o < 64; o <<= 1) {
            s  += __shfl_xor(s, o);
            sq += __shfl_xor(sq, o);
        }
        int w = tid >> 6;
        if ((tid & 63) == 0) { red[w] = s; red[4 + w] = sq; }
        __syncthreads();
        float ts = red[0] + red[1] + red[2] + red[3];
        float tq = red[4] + red[5] + red[6] + red[7];
        float mu  = ts * (1.f / DM);
        float var = tq * (1.f / DM) - mu * mu;
        float inv = rsqrtf(var + 1e-5f);
        __hip_bfloat16* o0 = xn + (size_t)row * DM;
        o0[tid]       = __float2bfloat16((v0 - mu) * inv * g[tid]       + be[tid]);
        o0[tid + 256] = __float2bfloat16((v1 - mu) * inv * g[tid + 256] + be[tid + 256]);
        return;
    }
    int b2 = bid - NROWS;
    const float* in; __hip_bfloat16* out; int R, Cc, bx, by;
    if (b2 < 256)      { in = Wi; out = Ti; R = DM; Cc = 2 * DI; bx = b2 & 31; by = b2 >> 5; }
    else if (b2 < 384) { int b3 = b2 - 256; in = Wo; out = To; R = DI; Cc = DM;   bx = b3 & 7; by = b3 >> 3; }
    else               { int b3 = b2 - 384; in = Wx; out = Tx; R = DI; Cc = XDBW; bx = b3 % 3; by = b3 / 3; }
    int r0 = by * 64, c0 = bx * 64;
    #pragma unroll
    for (int i = tid; i < 4096; i += 256) {
        int r = i >> 6, c = i & 63;
        tile[r][c] = (r0 + r < R && c0 + c < Cc) ? in[(size_t)(r0 + r) * Cc + c0 + c] : 0.f;
    }
    __syncthreads();
    #pragma unroll
    for (int i = tid; i < 4096; i += 256) {
        int c = i >> 6, r = i & 63;
        if (r0 + r < R && c0 + c < Cc)
            out[(size_t)(c0 + c) * R + r0 + r] = __float2bfloat16(tile[r][c]);
    }
}

// ---------------- in_proj GEMM 128x128 tile, 512 thr, BK=64 (2 stacked 32-K panels) -----
__global__ __launch_bounds__(512) void gemm_inproj(const __hip_bfloat16* __restrict__ A,
                                                   const __hip_bfloat16* __restrict__ Bt,
                                                   __hip_bfloat16* __restrict__ xh,
                                                   __hip_bfloat16* __restrict__ zh,
                                                   int M, int N, int K) {
    __shared__ __hip_bfloat16 As[128 * 64];
    __shared__ __hip_bfloat16 Bs[128 * 64];
    const int tid  = threadIdx.x;
    const int wave = tid >> 6, lane = tid & 63;
    const int m0 = blockIdx.y * 128, n0 = blockIdx.x * 128;
    const int wm = (wave >> 2) * 64, wn = (wave & 3) * 32;

    floatx4 acc[4][2] = {};

    const int arow16 = lane & 15;
    const int kgrp   = lane >> 4;

    for (int k0 = 0; k0 < K; k0 += 64) {
        #pragma unroll
        for (int p = 0; p < 2; ++p) {
            int j = tid + p * 512;            // 0..1023 chunk index
            int h = j >> 9, rs = j & 511;
            int row = rs >> 2, seg = rs & 3;
            const __hip_bfloat16* gA = A  + (size_t)(m0 + row) * K + k0 + h * 32 + seg * 8;
            const __hip_bfloat16* gB = Bt + (size_t)(n0 + row) * K + k0 + h * 32 + seg * 8;
            __hip_bfloat16* lA = As + (size_t)(wave * 64 + p * 512) * 8;
            __hip_bfloat16* lB = Bs + (size_t)(wave * 64 + p * 512) * 8;
            __builtin_amdgcn_global_load_lds(
                (const __attribute__((address_space(1))) void*)gA,
                (__attribute__((address_space(3))) void*)lA, 16, 0, 0);
            __builtin_amdgcn_global_load_lds(
                (const __attribute__((address_space(1))) void*)gB,
                (__attribute__((address_space(3))) void*)lB, 16, 0, 0);
        }
        __syncthreads();

        const shortx8* Asv = (const shortx8*)As;
        const shortx8* Bsv = (const shortx8*)Bs;
        #pragma unroll
        for (int h = 0; h < 2; ++h) {
            shortx8 a[4], b[2];
            #pragma unroll
            for (int i = 0; i < 4; ++i)
                a[i] = Asv[h * 512 + (wm + i * 16 + arow16) * 4 + kgrp];
            #pragma unroll
            for (int j = 0; j < 2; ++j)
                b[j] = Bsv[h * 512 + (wn + j * 16 + arow16) * 4 + kgrp];
            #pragma unroll
            for (int i = 0; i < 4; ++i)
                #pragma unroll
                for (int j = 0; j < 2; ++j)
                    acc[i][j] = __builtin_amdgcn_mfma_f32_16x16x32_bf16(a[i], b[j], acc[i][j], 0, 0, 0);
        }
        __syncthreads();
    }

    const int drow = (lane >> 4) * 4;
    const int dcol = lane & 15;
    const bool isz = (n0 >= DI);
    __hip_bfloat16* dst = isz ? zh : xh;
    const int coloff = isz ? DI : 0;
    #pragma unroll
    for (int i = 0; i < 4; ++i)
        #pragma unroll
        for (int j = 0; j < 2; ++j) {
            int rowb = m0 + wm + i * 16 + drow;
            int col  = n0 + wn + j * 16 + dcol - coloff;
            #pragma unroll
            for (int r = 0; r < 4; ++r)
                dst[(size_t)(rowb + r) * DI + col] = __float2bfloat16(acc[i][j][r]);
        }
}

// ---------------- bf16 MFMA GEMM 64x64 tile, 512 thr, split-K, BK=64 (2 panels) ---------
template<bool RES>
__global__ __launch_bounds__(512) void gemm64_sk(const __hip_bfloat16* __restrict__ A,
                                                 const __hip_bfloat16* __restrict__ Bt,
                                                 const float* __restrict__ Res,
                                                 float* __restrict__ C,
                                                 int M, int N, int K) {
    __shared__ __hip_bfloat16 As[2][64 * 64];
    __shared__ __hip_bfloat16 Bs[2][64 * 64];
    __shared__ float red[256 * 17];
    const int tid  = threadIdx.x;
    const int wave = tid >> 6, lane = tid & 63;
    const int g = wave >> 2, w2 = wave & 3;
    const int m0 = blockIdx.y * 64, n0 = blockIdx.x * 64;
    const int wm = (w2 >> 1) * 32, wn = (w2 & 1) * 32;

    floatx4 acc[2][2] = {};

    const int arow16 = lane & 15;
    const int kgrp   = lane >> 4;
    const int kbeg   = g * (K / 2);

    for (int kk = 0; kk < K / 2; kk += 64) {
        int k0 = kbeg + kk;
        #pragma unroll
        for (int p = 0; p < 2; ++p) {
            int j = (w2 * 64 + lane) + p * 256;   // 0..511 chunk index within group
            int h = j >> 8, rs = j & 255;
            int row = rs >> 2, seg = rs & 3;
            int brow = n0 + row; if (brow >= N) brow = N - 1;
            const __hip_bfloat16* gA = A  + (size_t)(m0 + row) * K + k0 + h * 32 + seg * 8;
            const __hip_bfloat16* gB = Bt + (size_t)brow * K + k0 + h * 32 + seg * 8;
            __hip_bfloat16* lA = As[g] + (size_t)(w2 * 64 + p * 256) * 8;
            __hip_bfloat16* lB = Bs[g] + (size_t)(w2 * 64 + p * 256) * 8;
            __builtin_amdgcn_global_load_lds(
                (const __attribute__((address_space(1))) void*)gA,
                (__attribute__((address_space(3))) void*)lA, 16, 0, 0);
            __builtin_amdgcn_global_load_lds(
                (const __attribute__((address_space(1))) void*)gB,
                (__attribute__((address_space(3))) void*)lB, 16, 0, 0);
        }
        __syncthreads();

        const shortx8* Asv = (const shortx8*)As[g];
        const shortx8* Bsv = (const shortx8*)Bs[g];
        #pragma unroll
        for (int h = 0; h < 2; ++h) {
            shortx8 a[2], b[2];
            #pragma unroll
            for (int i = 0; i < 2; ++i)
                a[i] = Asv[h * 256 + (wm + i * 16 + arow16) * 4 + kgrp];
            #pragma unroll
            for (int j = 0; j < 2; ++j)
                b[j] = Bsv[h * 256 + (wn + j * 16 + arow16) * 4 + kgrp];
            #pragma unroll
            for (int i = 0; i < 2; ++i)
                #pragma unroll
                for (int j = 0; j < 2; ++j)
                    acc[i][j] = __builtin_amdgcn_mfma_f32_16x16x32_bf16(a[i], b[j], acc[i][j], 0, 0, 0);
        }
        __syncthreads();
    }

    int rbase = (w2 * 64 + lane) * 17;
    if (g == 1) {
        #pragma unroll
        for (int i = 0; i < 2; ++i)
            #pragma unroll
            for (int j = 0; j < 2; ++j)
                *(float4*)&red[rbase + (i * 2 + j) * 4] =
                    make_float4(acc[i][j][0], acc[i][j][1], acc[i][j][2], acc[i][j][3]);
    }
    __syncthreads();
    if (g == 0) {
        const int drow = (lane >> 4) * 4;
        const int dcol = lane & 15;
        #pragma unroll
        for (int i = 0; i < 2; ++i)
            #pragma unroll
            for (int j = 0; j < 2; ++j) {
                float4 part = *(const float4*)&red[rbase + (i * 2 + j) * 4];
                int rowb = m0 + wm + i * 16 + drow;
                int col  = n0 + wn + j * 16 + dcol;
                if (col < N) {
                    #pragma unroll
                    for (int r = 0; r < 4; ++r) {
                        size_t idx = (size_t)(rowb + r) * N + col;
                        float v = acc[i][j][r] + (&part.x)[r];
                        if (RES) v += Res[idx];
                        C[idx] = v;
                    }
                }
            }
    }
}

// ---------------- Tiled conv + silu + transposes ----------------
__global__ __launch_bounds__(256) void conv_tile(const __hip_bfloat16* __restrict__ xh,
                                                 const __hip_bfloat16* __restrict__ zh,
                                                 const float* __restrict__ cw,
                                                 const float* __restrict__ cb,
                                                 __hip_bfloat16* __restrict__ xcv_bf,
                                                 __hip_bfloat16* __restrict__ xcvT,
                                                 __hip_bfloat16* __restrict__ zgT) {
    __shared__ float xt[67][68];
    __shared__ float tb[64][65];    // conv+silu result [t][d]
    __shared__ float tb2[64][65];   // silu(z) [t][d]
    int t0 = blockIdx.x * 64, d0 = blockIdx.y * 64, b = blockIdx.z;
    int tid = threadIdx.x;
    size_t rowbase = (size_t)b * Lseq;

    for (int i = tid; i < 67 * 16; i += 256) {
        int r = i >> 4, j = i & 15;
        int t = t0 - 3 + r;
        float4 v4 = make_float4(0.f, 0.f, 0.f, 0.f);
        if (t >= 0) {
            ushort4 u = *(const ushort4*)&xh[(rowbase + t) * DI + d0 + j * 4];
            v4 = make_float4(bf2f(u.x), bf2f(u.y), bf2f(u.z), bf2f(u.w));
        }
        *(float4*)&xt[r][j * 4] = v4;
    }
    for (int i = tid; i < 64 * 16; i += 256) {
        int r = i >> 4, j = i & 15;
        ushort4 u = *(const ushort4*)&zh[(rowbase + t0 + r) * DI + d0 + j * 4];
        tb2[r][j * 4 + 0] = silu_f(bf2f(u.x));
        tb2[r][j * 4 + 1] = silu_f(bf2f(u.y));
        tb2[r][j * 4 + 2] = silu_f(bf2f(u.z));
        tb2[r][j * 4 + 3] = silu_f(bf2f(u.w));
    }
    __syncthreads();

    {
        int d = tid & 63, tg = tid >> 6;
        float4 cwv = *(const float4*)&cw[(d0 + d) * 4];
        float cbv = cb[d0 + d];
        #pragma unroll
        for (int i = 0; i < 16; ++i) {
            int t = tg * 16 + i;
            float acc = cbv;
            #pragma unroll
            for (int k = 0; k < 4; ++k) acc += xt[t + k][d] * (&cwv.x)[k];
            float v = silu_f(acc);
            tb[t][d] = v;
            xcv_bf[(rowbase + t0 + t) * DI + d0 + d] = __float2bfloat16(v);
        }
    }
    __syncthreads();

    {
        int t2 = tid & 63, dg2 = tid >> 6;
        #pragma unroll
        for (int i = 0; i < 16; ++i) {
            int d = dg2 * 16 + i;
            size_t orow = ((size_t)(b * DI + d0 + d)) * Lseq + t0 + t2;
            xcvT[orow] = __float2bfloat16(tb[t2][d]);
            zgT[orow]  = __float2bfloat16(tb2[t2][d]);
        }
    }
}

// ---------------- delta = softplus(dt @ W_dt + b_dt) ----------------
__global__ void delta_kernel(const float* __restrict__ xdb, const float* __restrict__ Wdt,
                             const float* __restrict__ bdt, float* __restrict__ delta) {
    int row = blockIdx.y;
    int d = blockIdx.x * 256 + threadIdx.x;
    __shared__ float dtv[RNK];
    if (threadIdx.x < RNK) dtv[threadIdx.x] = xdb[(size_t)row * XDBW + threadIdx.x];
    __syncthreads();
    float acc = bdt[d];
    #pragma unroll
    for (int r = 0; r < RNK; ++r) acc += dtv[r] * Wdt[(size_t)r * DI + d];
    float sp = (acc > 20.f) ? acc : log1pf(__expf(acc));
    delta[(size_t)row * DI + d] = sp;
}

// ============ Chunked scan, phase 1: 2 d-channels per wave ============
__global__ __launch_bounds__(512) void scan_chunk1(
        const float* __restrict__ delta, const __hip_bfloat16* __restrict__ xcvT,
        const float* __restrict__ xdb, const float* __restrict__ A_log,
        float* __restrict__ hend, float* __restrict__ dsum) {
    __shared__ float Bsh[64][68];
    __shared__ float dsh[16][65];
    __shared__ float xsh[16][65];

    int blk = blockIdx.x;
    int dg  = blk & 63;             // DI/16 = 64
    int bc  = blk >> 6;             // b*NC + c
    int c = bc & (NC - 1), b = bc >> 4;
    int tid = threadIdx.x, w = tid >> 6, lane = tid & 63;
    int dbase = dg * 16;
    int r0 = b * Lseq + c * CH;

    #pragma unroll
    for (int k = 0; k < 2; ++k) {
        int idx = tid + k * 512;
        int row = idx >> 4, j4 = idx & 15;
        float4 v = *(const float4*)&xdb[(size_t)(r0 + row) * XDBW + RNK + j4 * 4];
        *(float4*)&Bsh[row][j4 * 4] = v;
    }
    #pragma unroll
    for (int k = 0; k < 2; ++k) {
        int i = tid + k * 512;
        int dd = i & 15, t = i >> 4;
        dsh[dd][t] = delta[(size_t)(r0 + t) * DI + dbase + dd];
    }
    #pragma unroll
    for (int k = 0; k < 2; ++k) {
        int i = tid + k * 512;
        int dd = i >> 6, t = i & 63;
        xsh[dd][t] = bf2f(((const unsigned short*)xcvT)[
            ((size_t)(b * DI + dbase + dd)) * Lseq + c * CH + t]);
    }
    __syncthreads();

    int d0 = dbase + w, d1 = dbase + 8 + w;
    float a0 = -__expf(A_log[d0 * DS + lane]);
    float a1 = -__expf(A_log[d1 * DS + lane]);
    float vd0 = dsh[w][lane],     vd1 = dsh[8 + w][lane];
    float vpx0 = vd0 * xsh[w][lane], vpx1 = vd1 * xsh[8 + w][lane];
    float h0 = 0.f, h1 = 0.f;
    #pragma unroll 16
    for (int t = 0; t < CH; ++t) {
        float Bt = Bsh[t][lane];
        h0 = h0 * __expf(rdl(vd0, t) * a0) + rdl(vpx0, t) * Bt;
        h1 = h1 * __expf(rdl(vd1, t) * a1) + rdl(vpx1, t) * Bt;
    }
    float S0 = vd0, S1 = vd1;
    #pragma unroll
    for (int o = 1; o < 64; o <<= 1) {
        S0 += __shfl_xor(S0, o);
        S1 += __shfl_xor(S1, o);
    }
    size_t cb = (size_t)bc * DI;
    hend[(cb + d0) * 64 + lane] = h0;
    hend[(cb + d1) * 64 + lane] = h1;
    if (lane == 0) {
        dsum[cb + d0] = S0;
        dsum[cb + d1] = S1;
    }
}

// ============ Chunked scan, phase 2 (fused stitch): recompute h_start in-block ==========
// h_start(c) replayed from hend/dsum of chunks 0..c-1 in the exact stitch order
// (bit-identical numerics). Saves the stitch launch + the 8 MB hstart buffer.
__global__ __launch_bounds__(512) void scan_chunk2(
        const float* __restrict__ delta, const __hip_bfloat16* __restrict__ xcvT,
        const float* __restrict__ xdb, const __hip_bfloat16* __restrict__ zgT,
        const float* __restrict__ A_log, const float* __restrict__ Dp,
        const float* __restrict__ hend, const float* __restrict__ dsum,
        __hip_bfloat16* __restrict__ y_row) {
    __shared__ unsigned int BCsh[64][65];  // [t][s] = (C & 0xFFFF0000) | (B >> 16)
    __shared__ float dsh[8][64];
    __shared__ float xsh[8][64];
    __shared__ float zsh[8][64];
    __shared__ float P[8][8 * 65];

    int blk = blockIdx.x;
    int dg  = blk & (DI / 8 - 1);
    int bc  = blk >> 7;
    int c = bc & (NC - 1), b = bc >> 4;
    int tid = threadIdx.x, w = tid >> 6, lane = tid & 63;
    int d = dg * 8 + w;
    int r0 = b * Lseq + c * CH;

    #pragma unroll
    for (int k = 0; k < 2; ++k) {
        int i = tid + k * 512;
        int t = i >> 4, sg = i & 15;
        const float* rowp = &xdb[(size_t)(r0 + t) * XDBW + RNK];
        float4 bv = *(const float4*)&rowp[sg * 4];
        float4 cv = *(const float4*)&rowp[DS + sg * 4];
        uint4 pk;
        #pragma unroll
        for (int j = 0; j < 4; ++j) {
            unsigned int bb = __float_as_uint((&bv.x)[j]);
            unsigned int cc2 = __float_as_uint((&cv.x)[j]);
            (&pk.x)[j] = (cc2 & 0xFFFF0000u) | (bb >> 16);
        }
        *(uint4*)&BCsh[t][sg * 4] = pk;
    }
    {
        int t = tid >> 3, ww = tid & 7;
        dsh[ww][t] = delta[(size_t)(r0 + t) * DI + dg * 8 + ww];
        size_t trow = ((size_t)(b * DI + d)) * Lseq + c * CH + lane;
        xsh[w][lane] = bf2f(((const unsigned short*)xcvT)[trow]);
        zsh[w][lane] = bf2f(((const unsigned short*)zgT)[trow]);   // already silu'd
    }
    __syncthreads();

    float a  = -__expf(A_log[d * DS + lane]);
    float Dv = Dp[d];
    float vd  = dsh[w][lane];
    float vpx = vd * xsh[w][lane];

    // fused stitch: replay chunks 0..c-1 (wave-uniform trip count)
    float h = 0.f;
    for (int j = 0; j < c; ++j) {
        size_t cbj = (size_t)(b * NC + j) * DI + d;
        float he = hend[cbj * 64 + lane];
        float S  = dsum[cbj];
        h = he + __expf(a * S) * h;
    }

    float* Pw = P[w];
    float yreg = 0.f;
    const int tr = lane & 7, q = lane >> 3;

    #pragma unroll
    for (int t8 = 0; t8 < 8; ++t8) {
        #pragma unroll
        for (int tt = 0; tt < 8; ++tt) {
            int t = t8 * 8 + tt;
            unsigned int bcp = BCsh[t][lane];
            float Bt = __uint_as_float(bcp << 16);
            float Ct = __uint_as_float(bcp & 0xFFFF0000u);
            float dt_ = rdl(vd, t);
            float px  = rdl(vpx, t);
            h = h * __expf(dt_ * a) + px * Bt;
            Pw[tt * 65 + lane] = h * Ct;
        }
        float sacc = 0.f;
        #pragma unroll
        for (int j = 0; j < 8; ++j) sacc += Pw[tr * 65 + q * 8 + j];
        sacc += __shfl_xor(sacc, 8);
        sacc += __shfl_xor(sacc, 16);
        sacc += __shfl_xor(sacc, 32);
        if (q == t8) yreg = sacc;
    }

    float yv = (yreg + xsh[w][lane] * Dv) * zsh[w][lane];

    __syncthreads();
    float* T = (float*)P;
    T[lane * 9 + w] = yv;
    __syncthreads();
    {
        int t = tid >> 3, dd = tid & 7;
        float v = T[t * 9 + dd];
        y_row[(size_t)(r0 + t) * DI + dg * 8 + dd] = __float2bfloat16(v);
    }
}

extern "C" void kernel_launch(void* const* d_in, const int* in_sizes, int n_in,
                              void* d_out, int out_size, void* d_ws, size_t ws_size,
                              hipStream_t stream) {
    const float* frames = (const float*)d_in[0];
    const float* gamma  = (const float*)d_in[1];
    const float* beta   = (const float*)d_in[2];
    const float* W_in   = (const float*)d_in[3];
    const float* conv_w = (const float*)d_in[4];
    const float* conv_b = (const float*)d_in[5];
    const float* W_x    = (const float*)d_in[6];
    const float* W_dt   = (const float*)d_in[7];
    const float* b_dt   = (const float*)d_in[8];
    const float* A_log  = (const float*)d_in[9];
    const float* Dp     = (const float*)d_in[10];
    const float* W_out  = (const float*)d_in[11];
    float* out = (float*)d_out;

    // workspace carve-up (bytes)
    char* ws = (char*)d_ws;
    __hip_bfloat16* xn_bf  = (__hip_bfloat16*)ws; ws += (size_t)NROWS * DM * 2;
    __hip_bfloat16* Wt_in  = (__hip_bfloat16*)ws; ws += (size_t)(2 * DI) * DM * 2;
    __hip_bfloat16* Wt_out = (__hip_bfloat16*)ws; ws += (size_t)DM * DI * 2;
    __hip_bfloat16* Wt_x   = (__hip_bfloat16*)ws; ws += (size_t)XDBW * DI * 2;
    __hip_bfloat16* y_row  = (__hip_bfloat16*)ws; ws += (size_t)NROWS * DI * 2;
    __hip_bfloat16* xcv_bf = (__hip_bfloat16*)ws; ws += (size_t)NROWS * DI * 2;
    __hip_bfloat16* xh     = (__hip_bfloat16*)ws; ws += (size_t)NROWS * DI * 2;
    __hip_bfloat16* zh     = (__hip_bfloat16*)ws; ws += (size_t)NROWS * DI * 2;
    __hip_bfloat16* xcvT   = (__hip_bfloat16*)ws; ws += (size_t)NROWS * DI * 2;
    __hip_bfloat16* zgT    = (__hip_bfloat16*)ws; ws += (size_t)NROWS * DI * 2;
    float* xdb    = (float*)ws;  ws += (size_t)NROWS * XDBW * 4;
    float* delta  = (float*)ws;  ws += (size_t)NROWS * DI * 4;
    float* hend   = (float*)ws;  ws += (size_t)Bn * NC * DI * 64 * 4;
    float* dsum   = (float*)ws;  ws += (size_t)Bn * NC * DI * 4;

    // fused LN + weight transposes
    prep_kernel<<<NROWS + 432, 256, 0, stream>>>(frames, gamma, beta, W_in, W_out, W_x,
                                                 xn_bf, Wt_in, Wt_out, Wt_x);

    // in_proj -> bf16 x-half / z-half (BK=64)
    gemm_inproj<<<dim3(2 * DI / 128, NROWS / 128), 512, 0, stream>>>(
        xn_bf, Wt_in, xh, zh, NROWS, 2 * DI, DM);

    // conv + silu + transposes
    conv_tile<<<dim3(Lseq / 64, DI / 64, Bn), 256, 0, stream>>>(
        xh, zh, conv_w, conv_b, xcv_bf, xcvT, zgT);

    // xdb = xcv @ W_x  (M=2048, N=160, K=1024, BK=64 split-K)
    gemm64_sk<false><<<dim3((XDBW + 63) / 64, NROWS / 64), 512, 0, stream>>>(
        xcv_bf, Wt_x, nullptr, xdb, NROWS, XDBW, DI);

    delta_kernel<<<dim3(DI / 256, NROWS), 256, 0, stream>>>(xdb, W_dt, b_dt, delta);

    // chunked selective scan (stitch fused into chunk2)
    scan_chunk1<<<Bn * NC * (DI / 16), 512, 0, stream>>>(delta, xcvT, xdb, A_log, hend, dsum);
    scan_chunk2<<<Bn * NC * (DI / 8), 512, 0, stream>>>(delta, xcvT, xdb, zgT, A_log, Dp,
                                                        hend, dsum, y_row);

    // out_proj: out = y_row @ W_out + frames (BK=64 split-K)
    gemm64_sk<true><<<dim3(DM / 64, NROWS / 64), 512, 0, stream>>>(
        y_row, Wt_out, frames, out, NROWS, DM, DI);
}